// Round 6
// baseline (733.922 us; speedup 1.0000x reference)
//
#include <hip/hip_runtime.h>
#include <hip/hip_bf16.h>

#define BQ 4
#define NQT 1024
#define DM 256
#define HSA 8
#define DHSA 32
#define CAH 8
#define CADH 64
#define CAI 512
#define NPT 4
#define DFFN 1024
#define TT 4
#define HH 64
#define WW 64
#define LVOL 16384

using bf16 = __hip_bfloat16;
typedef __attribute__((ext_vector_type(4))) float fx4;
typedef __attribute__((ext_vector_type(8))) short s8v;
typedef __attribute__((ext_vector_type(4))) short s4v;

__device__ __forceinline__ float b2f(bf16 v) { return __bfloat162float(v); }
__device__ __forceinline__ bf16  f2b(float v) { return __float2bfloat16(v); }
__device__ __forceinline__ short f2bs(float v) {
  bf16 b = __float2bfloat16(v);
  return *reinterpret_cast<short*>(&b);
}

__device__ __forceinline__ float wave_sum64(float v) {
#pragma unroll
  for (int o = 32; o >= 1; o >>= 1) v += __shfl_xor(v, o, 64);
  return v;
}

__device__ __forceinline__ s8v pack8(float4 a, float4 b) {
  return (s8v){f2bs(a.x), f2bs(a.y), f2bs(a.z), f2bs(a.w),
               f2bs(b.x), f2bs(b.y), f2bs(b.z), f2bs(b.w)};
}

// async global->LDS, 16B per lane; lds base must be wave-uniform.
__device__ __forceinline__ void gl_lds16(const void* g, void* l) {
  __builtin_amdgcn_global_load_lds(
      (const __attribute__((address_space(1))) unsigned int*)g,
      (__attribute__((address_space(3))) unsigned int*)l, 16, 0, 0);
}

// ---------------------------------------------------------------------------
// Weight pre-transpose + bf16 cast: W[K][N] f32 -> Wt[N][K] bf16.
// ---------------------------------------------------------------------------
template <int KSH>
__global__ __launch_bounds__(256) void wtrans_k(const float* __restrict__ W,
                                               short* __restrict__ Wt, int N) {
  const int i = blockIdx.x * 256 + threadIdx.x;  // i = n*K + k
  const int k = i & ((1 << KSH) - 1);
  const int n = i >> KSH;
  Wt[i] = f2bs(W[(size_t)k * N + n]);
}

// ---------------------------------------------------------------------------
// Elementwise prep: O = bf16(A (+B)). 4x manual unroll with INDEPENDENT
// iterations: 4 (8 for DUAL) float4 loads in flight per thread before any
// dependent store -> MLP to cover ~900cy HBM latency (R5 postmortem: the
// single-iteration version was request-starved at 3 TB/s device).
// ---------------------------------------------------------------------------
template <int DUAL>
__global__ __launch_bounds__(256) void prep_k(const float* __restrict__ A,
                                              const float* __restrict__ B,
                                              short* __restrict__ O, int n4) {
  const int tot = gridDim.x * 256;
  int i = blockIdx.x * 256 + threadIdx.x;
  for (; i + 3 * tot < n4; i += 4 * tot) {
    const int i0 = i, i1 = i + tot, i2 = i + 2 * tot, i3 = i + 3 * tot;
    float4 a0 = ((const float4*)A)[i0];
    float4 a1 = ((const float4*)A)[i1];
    float4 a2 = ((const float4*)A)[i2];
    float4 a3 = ((const float4*)A)[i3];
    if (DUAL) {
      const float4 b0 = ((const float4*)B)[i0];
      const float4 b1 = ((const float4*)B)[i1];
      const float4 b2 = ((const float4*)B)[i2];
      const float4 b3 = ((const float4*)B)[i3];
      a0.x += b0.x; a0.y += b0.y; a0.z += b0.z; a0.w += b0.w;
      a1.x += b1.x; a1.y += b1.y; a1.z += b1.z; a1.w += b1.w;
      a2.x += b2.x; a2.y += b2.y; a2.z += b2.z; a2.w += b2.w;
      a3.x += b3.x; a3.y += b3.y; a3.z += b3.z; a3.w += b3.w;
    }
    ((s4v*)O)[i0] = (s4v){f2bs(a0.x), f2bs(a0.y), f2bs(a0.z), f2bs(a0.w)};
    ((s4v*)O)[i1] = (s4v){f2bs(a1.x), f2bs(a1.y), f2bs(a1.z), f2bs(a1.w)};
    ((s4v*)O)[i2] = (s4v){f2bs(a2.x), f2bs(a2.y), f2bs(a2.z), f2bs(a2.w)};
    ((s4v*)O)[i3] = (s4v){f2bs(a3.x), f2bs(a3.y), f2bs(a3.z), f2bs(a3.w)};
  }
  for (; i < n4; i += tot) {
    float4 a = ((const float4*)A)[i];
    if (DUAL) {
      const float4 b = ((const float4*)B)[i];
      a.x += b.x; a.y += b.y; a.z += b.z; a.w += b.w;
    }
    ((s4v*)O)[i] = (s4v){f2bs(a.x), f2bs(a.y), f2bs(a.z), f2bs(a.w)};
  }
}

// ---------------------------------------------------------------------------
// bf16 MFMA GEMM (m97-structure): C[M,N] = A[M,K](bf16) @ Wt[N,K](bf16) + b.
// 128x128 tile, BK=32, 256 threads = 4 waves; global_load_lds width=16,
// double-buffered, one barrier per K-step. XCD swizzle (T1). Output bf16.
// ---------------------------------------------------------------------------
__global__ __launch_bounds__(256) void bgemm_k(
    const short* __restrict__ A, const short* __restrict__ Wt,
    const float* __restrict__ bias, bf16* __restrict__ Cout,
    int M, int N, int K) {
  __shared__ short As[2][128 * 32];  // [m][k] linear (gl_lds layout)
  __shared__ short Bs[2][128 * 32];  // [n][k] linear
  const int tid = threadIdx.x;
  const int lane = tid & 63, w = tid >> 6;
  const int wr = w >> 1, wc = w & 1;
  const int lm = lane & 15, quad = lane >> 4;
  const int nwg = gridDim.x * gridDim.y;
  const int ib = blockIdx.y * gridDim.x + blockIdx.x;
  const int id = (ib & 7) * (nwg >> 3) + (ib >> 3);
  const int m0 = (id / gridDim.x) * 128;
  const int n0 = (id % gridDim.x) * 128;

  const int srow = lane >> 2;        // 0..15 within 16-row chunk
  const int scol = (lane & 3) * 8;   // k-chunk of 8 shorts (16 B)
  const size_t arow = (size_t)(m0 + w * 32 + srow);
  const size_t brow = (size_t)(n0 + w * 32 + srow);

  fx4 acc[4][4] = {};
  const int nt = K / 32;
  int cur = 0;
  {
    gl_lds16(&A[arow * K + scol], &As[0][(w * 32) * 32]);
    gl_lds16(&A[(arow + 16) * K + scol], &As[0][(w * 32 + 16) * 32]);
    gl_lds16(&Wt[brow * K + scol], &Bs[0][(w * 32) * 32]);
    gl_lds16(&Wt[(brow + 16) * K + scol], &Bs[0][(w * 32 + 16) * 32]);
  }
  __syncthreads();
  for (int t = 0; t < nt; t++) {
    if (t + 1 < nt) {
      const int k0 = (t + 1) * 32;
      gl_lds16(&A[arow * K + k0 + scol], &As[cur ^ 1][(w * 32) * 32]);
      gl_lds16(&A[(arow + 16) * K + k0 + scol], &As[cur ^ 1][(w * 32 + 16) * 32]);
      gl_lds16(&Wt[brow * K + k0 + scol], &Bs[cur ^ 1][(w * 32) * 32]);
      gl_lds16(&Wt[(brow + 16) * K + k0 + scol], &Bs[cur ^ 1][(w * 32 + 16) * 32]);
    }
    s8v af[4], bfr[4];
#pragma unroll
    for (int f = 0; f < 4; f++) {
      af[f] = *(s8v*)&As[cur][(wr * 64 + f * 16 + lm) * 32 + quad * 8];
      bfr[f] = *(s8v*)&Bs[cur][(wc * 64 + f * 16 + lm) * 32 + quad * 8];
    }
#pragma unroll
    for (int fm = 0; fm < 4; fm++)
#pragma unroll
      for (int fn = 0; fn < 4; fn++)
        acc[fm][fn] = __builtin_amdgcn_mfma_f32_16x16x32_bf16(
            af[fm], bfr[fn], acc[fm][fn], 0, 0, 0);
    __syncthreads();
    cur ^= 1;
  }
#pragma unroll
  for (int fn = 0; fn < 4; fn++) {
    const int n = n0 + wc * 64 + fn * 16 + lm;
    const float bb = bias[n];
#pragma unroll
    for (int fm = 0; fm < 4; fm++) {
      const int mbase = m0 + wr * 64 + fm * 16 + quad * 4;
#pragma unroll
      for (int r = 0; r < 4; r++)
        Cout[(size_t)(mbase + r) * N + n] = f2b(acc[fm][fn][r] + bb);
    }
  }
}

// ---------------------------------------------------------------------------
// MFMA GEMM (R2 version): C[M,N] = (A (+A2))[M,K] @ W[K,N] + bias.
// ---------------------------------------------------------------------------
template <int DUAL, int RELU, int OUTBF>
__global__ __launch_bounds__(256) void mgemm_k(
    const float* __restrict__ A, const float* __restrict__ A2,
    const short* __restrict__ Wt, const float* __restrict__ bias,
    void* __restrict__ Cout, int M, int N, int K) {
  __shared__ short As[2][128 * 40];
  __shared__ short Bs[2][128 * 40];
  const int tid = threadIdx.x;
  const int lane = tid & 63, w = tid >> 6;
  const int wr = w >> 1, wc = w & 1;
  const int lm = lane & 15, quad = lane >> 4;
  const int nwg = gridDim.x * gridDim.y;
  const int ib = blockIdx.y * gridDim.x + blockIdx.x;
  const int id = (ib & 7) * (nwg >> 3) + (ib >> 3);
  const int m0 = (id / gridDim.x) * 128;
  const int n0 = (id % gridDim.x) * 128;

  const int am = tid >> 3, ak = (tid & 7) * 4;

  float4 pa[4], pa2[4];
  s8v pb[2];
  auto loadT = [&](int k0) {
#pragma unroll
    for (int i = 0; i < 4; i++) {
      pa[i] = *(const float4*)&A[(size_t)(m0 + am + i * 32) * K + k0 + ak];
      if (DUAL)
        pa2[i] = *(const float4*)&A2[(size_t)(m0 + am + i * 32) * K + k0 + ak];
    }
#pragma unroll
    for (int i = 0; i < 2; i++) {
      int unit = tid + i * 256;
      pb[i] = *(const s8v*)&Wt[(size_t)(n0 + (unit >> 2)) * K + k0 +
                               (unit & 3) * 8];
    }
  };
  auto stageT = [&](int buf) {
#pragma unroll
    for (int i = 0; i < 4; i++) {
      float x0 = pa[i].x, x1 = pa[i].y, x2 = pa[i].z, x3 = pa[i].w;
      if (DUAL) { x0 += pa2[i].x; x1 += pa2[i].y; x2 += pa2[i].z; x3 += pa2[i].w; }
      s4v sv = {f2bs(x0), f2bs(x1), f2bs(x2), f2bs(x3)};
      *(s4v*)&As[buf][(am + i * 32) * 40 + ak] = sv;
    }
#pragma unroll
    for (int i = 0; i < 2; i++) {
      int unit = tid + i * 256;
      *(s8v*)&Bs[buf][(unit >> 2) * 40 + (unit & 3) * 8] = pb[i];
    }
  };

  fx4 acc[4][4] = {};
  loadT(0);
  stageT(0);
  __syncthreads();
  int cur = 0;
  for (int k0 = 0; k0 < K; k0 += 32) {
    const int more = (k0 + 32 < K);
    if (more) loadT(k0 + 32);
    s8v af[4], bfr[4];
#pragma unroll
    for (int f = 0; f < 4; f++) {
      af[f] = *(s8v*)&As[cur][(wr * 64 + f * 16 + lm) * 40 + quad * 8];
      bfr[f] = *(s8v*)&Bs[cur][(wc * 64 + f * 16 + lm) * 40 + quad * 8];
    }
#pragma unroll
    for (int fm = 0; fm < 4; fm++)
#pragma unroll
      for (int fn = 0; fn < 4; fn++)
        acc[fm][fn] = __builtin_amdgcn_mfma_f32_16x16x32_bf16(
            af[fm], bfr[fn], acc[fm][fn], 0, 0, 0);
    if (more) stageT(cur ^ 1);
    __syncthreads();
    cur ^= 1;
  }
#pragma unroll
  for (int fn = 0; fn < 4; fn++) {
    const int n = n0 + wc * 64 + fn * 16 + lm;
    const float bb = bias[n];
#pragma unroll
    for (int fm = 0; fm < 4; fm++) {
      const int mbase = m0 + wr * 64 + fm * 16 + quad * 4;
#pragma unroll
      for (int r = 0; r < 4; r++) {
        float v = acc[fm][fn][r] + bb;
        if (RELU) v = fmaxf(v, 0.0f);
        const size_t off = (size_t)(mbase + r) * N + n;
        if (OUTBF)
          ((bf16*)Cout)[off] = f2b(v);
        else
          ((float*)Cout)[off] = v;
      }
    }
  }
}

// ---------------------------------------------------------------------------
// Flash-style MFMA self-attention, KV-split by 2 (flash-decoding).
// ---------------------------------------------------------------------------
__global__ __launch_bounds__(256) void sa_flash_k(
    const float* __restrict__ qh, const float* __restrict__ kh,
    const float* __restrict__ vh, float* __restrict__ op0,
    float* __restrict__ op1, float* __restrict__ mlb) {
  __shared__ short Ks[64 * 72];
  __shared__ short Vt[32 * 72];
  __shared__ short Ps[64 * 72];
  const int qt = blockIdx.x, h = blockIdx.y;
  const int b = blockIdx.z >> 1, half = blockIdx.z & 1;
  const int tid = threadIdx.x;
  const int w = tid >> 6, lane = tid & 63;
  const int lm = lane & 15, quad = lane >> 4;
  const size_t rowbase = (size_t)(b * NQT) * DM + h * DHSA;
  float* __restrict__ opart = half ? op1 : op0;
  float* __restrict__ ml = mlb + (size_t)half * (32768 * 2);

  s8v aq;
  {
    const int qrow = qt * 64 + w * 16 + lm;
    const float* qp = &qh[rowbase + (size_t)qrow * DM + quad * 8];
    const float4 q0 = *(const float4*)qp;
    const float4 q1 = *(const float4*)(qp + 4);
    const float sc = 0.17677669529663687f;
    aq = (s8v){f2bs(q0.x * sc), f2bs(q0.y * sc), f2bs(q0.z * sc), f2bs(q0.w * sc),
               f2bs(q1.x * sc), f2bs(q1.y * sc), f2bs(q1.z * sc), f2bs(q1.w * sc)};
  }

  fx4 o0 = {}, o1 = {};
  float mrun[4] = {-1e30f, -1e30f, -1e30f, -1e30f};
  float lrun[4] = {0.f, 0.f, 0.f, 0.f};
  const int jr = tid >> 2;
  const int d0 = (tid & 3) * 8;

  for (int jt = half * 8; jt < half * 8 + 8; jt++) {
    __syncthreads();
    {
      const size_t rb = rowbase + (size_t)(jt * 64 + jr) * DM + d0;
      const float4 k0 = *(const float4*)&kh[rb];
      const float4 k1 = *(const float4*)&kh[rb + 4];
      *(s8v*)&Ks[jr * 72 + d0] = pack8(k0, k1);
      const float4 v0 = *(const float4*)&vh[rb];
      const float4 v1 = *(const float4*)&vh[rb + 4];
      Vt[(d0 + 0) * 72 + jr] = f2bs(v0.x);
      Vt[(d0 + 1) * 72 + jr] = f2bs(v0.y);
      Vt[(d0 + 2) * 72 + jr] = f2bs(v0.z);
      Vt[(d0 + 3) * 72 + jr] = f2bs(v0.w);
      Vt[(d0 + 4) * 72 + jr] = f2bs(v1.x);
      Vt[(d0 + 5) * 72 + jr] = f2bs(v1.y);
      Vt[(d0 + 6) * 72 + jr] = f2bs(v1.z);
      Vt[(d0 + 7) * 72 + jr] = f2bs(v1.w);
    }
    __syncthreads();
    fx4 s[4];
    const fx4 zero = {};
#pragma unroll
    for (int nf = 0; nf < 4; nf++) {
      s8v kb = *(const s8v*)&Ks[(nf * 16 + lm) * 72 + quad * 8];
      s[nf] = __builtin_amdgcn_mfma_f32_16x16x32_bf16(aq, kb, zero, 0, 0, 0);
    }
#pragma unroll
    for (int r = 0; r < 4; r++) {
      float mx = fmaxf(fmaxf(s[0][r], s[1][r]), fmaxf(s[2][r], s[3][r]));
#pragma unroll
      for (int off = 8; off >= 1; off >>= 1)
        mx = fmaxf(mx, __shfl_xor(mx, off, 64));
      const float mnew = fmaxf(mrun[r], mx);
      const float corr = expf(mrun[r] - mnew);
      mrun[r] = mnew;
      float p0 = expf(s[0][r] - mnew);
      float p1 = expf(s[1][r] - mnew);
      float p2 = expf(s[2][r] - mnew);
      float p3 = expf(s[3][r] - mnew);
      float rs = p0 + p1 + p2 + p3;
#pragma unroll
      for (int off = 8; off >= 1; off >>= 1) rs += __shfl_xor(rs, off, 64);
      lrun[r] = lrun[r] * corr + rs;
      o0[r] *= corr;
      o1[r] *= corr;
      s[0][r] = p0; s[1][r] = p1; s[2][r] = p2; s[3][r] = p3;
    }
#pragma unroll
    for (int nf = 0; nf < 4; nf++)
#pragma unroll
      for (int r = 0; r < 4; r++)
        Ps[(w * 16 + quad * 4 + r) * 72 + nf * 16 + lm] = f2bs(s[nf][r]);
#pragma unroll
    for (int ks = 0; ks < 2; ks++) {
      s8v pf = *(const s8v*)&Ps[(w * 16 + lm) * 72 + ks * 32 + quad * 8];
      s8v vb0 = *(const s8v*)&Vt[lm * 72 + ks * 32 + quad * 8];
      s8v vb1 = *(const s8v*)&Vt[(16 + lm) * 72 + ks * 32 + quad * 8];
      o0 = __builtin_amdgcn_mfma_f32_16x16x32_bf16(pf, vb0, o0, 0, 0, 0);
      o1 = __builtin_amdgcn_mfma_f32_16x16x32_bf16(pf, vb1, o1, 0, 0, 0);
    }
  }
#pragma unroll
  for (int r = 0; r < 4; r++) {
    const int row = qt * 64 + w * 16 + quad * 4 + r;
    const size_t base = rowbase + (size_t)row * DM;
    opart[base + lm] = o0[r];
    opart[base + 16 + lm] = o1[r];
    if (lm == 0) {
      const int rowid = (b * 8 + h) * 1024 + row;
      ml[(size_t)rowid * 2] = mrun[r];
      ml[(size_t)rowid * 2 + 1] = lrun[r];
    }
  }
}

// Merge the two KV-halves: out = (o0*w0 + o1*w1) / (l0*w0 + l1*w1).
__global__ __launch_bounds__(256) void sa_merge_k(
    const float* __restrict__ op0, const float* __restrict__ op1,
    const float* __restrict__ mlb, float* __restrict__ outp) {
  const int t = blockIdx.x * 256 + threadIdx.x;  // 0..1048575
  const int d = t & 31;
  const int rowid = t >> 5;  // (b*8+h)*1024 + n
  const int n = rowid & 1023, h = (rowid >> 10) & 7, b = rowid >> 13;
  const size_t addr = ((size_t)(b * NQT + n)) * DM + h * DHSA + d;
  const float m0 = mlb[(size_t)rowid * 2], l0 = mlb[(size_t)rowid * 2 + 1];
  const float m1 = mlb[65536 + (size_t)rowid * 2];
  const float l1 = mlb[65536 + (size_t)rowid * 2 + 1];
  const float M = fmaxf(m0, m1);
  const float w0 = expf(m0 - M), w1 = expf(m1 - M);
  const float inv = 1.0f / (l0 * w0 + l1 * w1);
  outp[addr] = (op0[addr] * w0 + op1[addr] * w1) * inv;
}

// ---------------------------------------------------------------------------
// ref = sigmoid(x1 @ Wref + bref), off = x1 @ Woff + boff  (per query row)
// ---------------------------------------------------------------------------
__global__ __launch_bounds__(128) void refoff_k(
    const float* __restrict__ x1, const float* __restrict__ Wref,
    const float* __restrict__ bref, const float* __restrict__ Woff,
    const float* __restrict__ boff, float* __restrict__ refb,
    float* __restrict__ offb) {
  __shared__ float xs[256];
  const int row = blockIdx.x;
  const int tid = threadIdx.x;
  xs[tid] = x1[(size_t)row * DM + tid];
  xs[tid + 128] = x1[(size_t)row * DM + tid + 128];
  __syncthreads();
  if (tid < 3) {
    float s = bref[tid];
    for (int d = 0; d < 256; d++) s = fmaf(xs[d], Wref[d * 3 + tid], s);
    refb[(size_t)row * 3 + tid] = 1.0f / (1.0f + expf(-s));
  } else if (tid < 99) {
    int o = tid - 3;
    float s = boff[o];
    for (int d = 0; d < 256; d++) s = fmaf(xs[d], Woff[d * 96 + o], s);
    offb[(size_t)row * 96 + o] = s;
  }
}

// ---------------------------------------------------------------------------
// Shared trilinear corner computation for one (bn, h).
// ---------------------------------------------------------------------------
__device__ __forceinline__ void calc_corners(
    const float* __restrict__ refb, const float* __restrict__ offb, int bn,
    int h, int (&idxs)[NPT][8], float (&wts)[NPT][8]) {
  const float rt = refb[bn * 3 + 0], ry = refb[bn * 3 + 1], rx = refb[bn * 3 + 2];
  const float* ofp = &offb[(size_t)bn * 96 + h * 12];
#pragma unroll
  for (int p = 0; p < NPT; p++) {
    float lt = rt + ofp[p * 3 + 0] * 0.5f;      // OFFSET_SCALE / T
    float ly = ry + ofp[p * 3 + 1] * 0.03125f;  // OFFSET_SCALE / H
    float lx = rx + ofp[p * 3 + 2] * 0.03125f;  // OFFSET_SCALE / W
    float pt = fminf(fmaxf(lt, 0.f), 1.f) * (TT - 1);
    float py = fminf(fmaxf(ly, 0.f), 1.f) * (HH - 1);
    float px = fminf(fmaxf(lx, 0.f), 1.f) * (WW - 1);
    float f0t = floorf(pt), f0y = floorf(py), f0x = floorf(px);
    float frt = pt - f0t, fry = py - f0y, frx = px - f0x;
    int t0 = (int)f0t, y0 = (int)f0y, x0 = (int)f0x;
    int t1 = min(t0 + 1, TT - 1), y1 = min(y0 + 1, HH - 1), x1 = min(x0 + 1, WW - 1);
    float wt0 = 1.f - frt, wy0 = 1.f - fry, wx0 = 1.f - frx;
#pragma unroll
    for (int c = 0; c < 8; c++) {
      int dt = c >> 2, dy = (c >> 1) & 1, dx = c & 1;
      int ct = dt ? t1 : t0, cy = dy ? y1 : y0, cx = dx ? x1 : x0;
      idxs[p][c] = ct * (HH * WW) + cy * WW + cx;
      wts[p][c] = (dt ? frt : wt0) * (dy ? fry : wy0) * (dx ? frx : wx0);
    }
  }
}

// ---------------------------------------------------------------------------
// Sample k-volume at the 4 points, dot with q -> 4 logits into slots.
// ---------------------------------------------------------------------------
__global__ __launch_bounds__(256) void ca_logits_k(
    const float* __restrict__ qh, const float* __restrict__ refb,
    const float* __restrict__ offb, const bf16* __restrict__ vol,
    float* __restrict__ logits, int slot) {
  const int wid = (blockIdx.x * blockDim.x + threadIdx.x) >> 6;  // 0..32767
  const int lane = threadIdx.x & 63;
  const int h = wid & 7;
  const int bn = wid >> 3;  // 0..4095
  const int b = bn >> 10;
  const float q = qh[(size_t)bn * CAI + h * CADH + lane];
  int idxs[NPT][8];
  float wts[NPT][8];
  calc_corners(refb, offb, bn, h, idxs, wts);
  const size_t volbase = (size_t)b * LVOL * CAI + h * CADH + lane;
  float* lp = logits + ((size_t)bn * CAH + h) * 8 + slot;
#pragma unroll
  for (int p = 0; p < NPT; p++) {
    float ks = 0.f;
#pragma unroll
    for (int c = 0; c < 8; c++)
      ks = fmaf(wts[p][c], b2f(vol[volbase + (size_t)idxs[p][c] * CAI]), ks);
    float li = wave_sum64(q * ks) * 0.125f;  // 1/sqrt(64)
    if (lane == p) lp[p] = li;
  }
}

// ---------------------------------------------------------------------------
// Joint softmax over the 8 logits (4 img + 4 flow) per (bn, h), in place.
// ---------------------------------------------------------------------------
__global__ __launch_bounds__(256) void ca_softmax_k(float* __restrict__ logits) {
  const int i = blockIdx.x * blockDim.x + threadIdx.x;  // 0..32767
  float* p = logits + (size_t)i * 8;
  float v[8], m = -1e30f;
#pragma unroll
  for (int j = 0; j < 8; j++) { v[j] = p[j]; m = fmaxf(m, v[j]); }
  float s = 0.f;
#pragma unroll
  for (int j = 0; j < 8; j++) { v[j] = expf(v[j] - m); s += v[j]; }
  const float inv = 1.0f / s;
#pragma unroll
  for (int j = 0; j < 8; j++) p[j] = v[j] * inv;
}

// ---------------------------------------------------------------------------
// Sample v-volume, weight by attn slots, accumulate into f32 acc.
// ---------------------------------------------------------------------------
template <int FIRST>
__global__ __launch_bounds__(256) void ca_acc_k(
    const float* __restrict__ refb, const float* __restrict__ offb,
    const bf16* __restrict__ vol, const float* __restrict__ attn,
    float* __restrict__ acc, int slot) {
  const int wid = (blockIdx.x * blockDim.x + threadIdx.x) >> 6;
  const int lane = threadIdx.x & 63;
  const int h = wid & 7;
  const int bn = wid >> 3;
  const int b = bn >> 10;
  int idxs[NPT][8];
  float wts[NPT][8];
  calc_corners(refb, offb, bn, h, idxs, wts);
  const size_t volbase = (size_t)b * LVOL * CAI + h * CADH + lane;
  const float* ap = attn + ((size_t)bn * CAH + h) * 8 + slot;
  const size_t off = (size_t)bn * CAI + h * CADH + lane;
  float a = FIRST ? 0.f : acc[off];
#pragma unroll
  for (int p = 0; p < NPT; p++) {
    float vs = 0.f;
#pragma unroll
    for (int c = 0; c < 8; c++)
      vs = fmaf(wts[p][c], b2f(vol[volbase + (size_t)idxs[p][c] * CAI]), vs);
    a = fmaf(ap[p], vs, a);
  }
  acc[off] = a;
}

// ---------------------------------------------------------------------------
// LayerNorm over 256 dims of (res + x); one wave per row; f32 in/out.
// ---------------------------------------------------------------------------
__global__ __launch_bounds__(256) void ln_k(
    const float* __restrict__ resv, const float* __restrict__ x,
    const float* __restrict__ g, const float* __restrict__ bb,
    float* __restrict__ of) {
  const int row = (blockIdx.x * blockDim.x + threadIdx.x) >> 6;
  const int lane = threadIdx.x & 63;
  const size_t base = (size_t)row * DM;
  float v[4];
#pragma unroll
  for (int i = 0; i < 4; i++) {
    int d = lane + i * 64;
    v[i] = resv[base + d] + x[base + d];
  }
  float s = wave_sum64(v[0] + v[1] + v[2] + v[3]);
  const float mean = s * (1.0f / 256.0f);
  float vs = 0.f;
#pragma unroll
  for (int i = 0; i < 4; i++) { float d0 = v[i] - mean; vs = fmaf(d0, d0, vs); }
  vs = wave_sum64(vs);
  const float rstd = rsqrtf(vs * (1.0f / 256.0f) + 1e-5f);
#pragma unroll
  for (int i = 0; i < 4; i++) {
    int d = lane + i * 64;
    of[base + d] = (v[i] - mean) * rstd * g[d] + bb[d];
  }
}

extern "C" void kernel_launch(void* const* d_in, const int* in_sizes, int n_in,
                              void* d_out, int out_size, void* d_ws,
                              size_t ws_size, hipStream_t stream) {
  const float* query = (const float*)d_in[0];
  const float* qpos = (const float*)d_in[1];
  const float* img = (const float*)d_in[2];
  const float* flow = (const float*)d_in[3];
  const float* pos = (const float*)d_in[4];
  const float* sa_Wq = (const float*)d_in[6];
  const float* sa_Wk = (const float*)d_in[7];
  const float* sa_Wv = (const float*)d_in[8];
  const float* sa_Wo = (const float*)d_in[9];
  const float* sa_bq = (const float*)d_in[10];
  const float* sa_bk = (const float*)d_in[11];
  const float* sa_bv = (const float*)d_in[12];
  const float* sa_bo = (const float*)d_in[13];
  const float* ln1_b = (const float*)d_in[14];
  const float* ln2_b = (const float*)d_in[15];
  const float* ln3_b = (const float*)d_in[16];
  const float* ln1_g = (const float*)d_in[17];
  const float* ln2_g = (const float*)d_in[18];
  const float* ln3_g = (const float*)d_in[19];
  const float* ca_Wq = (const float*)d_in[20];
  const float* ca_bq = (const float*)d_in[21];
  const float* ca_Wk = (const float*)d_in[22];
  const float* ca_bk = (const float*)d_in[23];
  const float* ca_Wv = (const float*)d_in[24];
  const float* ca_bv = (const float*)d_in[25];
  const float* ca_Wref = (const float*)d_in[26];
  const float* ca_bref = (const float*)d_in[27];
  const float* ca_Woff = (const float*)d_in[28];
  const float* ca_boff = (const float*)d_in[29];
  const float* ca_Wo = (const float*)d_in[30];
  const float* ca_bo = (const float*)d_in[31];
  const float* ffn_W1 = (const float*)d_in[32];
  const float* ffn_b1 = (const float*)d_in[33];
  const float* ffn_W2 = (const float*)d_in[34];
  const float* ffn_b2 = (const float*)d_in[35];

  const int MQ = BQ * NQT;   // 4096
  const int MV = BQ * LVOL;  // 65536
  const size_t MB = 1024 * 1024;

  char* r0 = (char*)d_ws;  // 64 MB time-shared region
  char* w = r0 + 64 * MB;
  auto alloc = [&](size_t n) {
    char* p = w;
    w += (n + 255) & ~(size_t)255;
    return p;
  };
  float* x1_f = (float*)alloc((size_t)MQ * DM * 4);
  float* ca_qh = (float*)alloc((size_t)MQ * CAI * 4);
  float* refb = (float*)alloc((size_t)MQ * 3 * 4);
  float* offb = (float*)alloc((size_t)MQ * 96 * 4);
  float* logits = (float*)alloc((size_t)MQ * CAH * 8 * 4);
  float* ca_acc = (float*)alloc((size_t)MQ * CAI * 4);
  // transposed bf16 weights [N][K]
  short* WtsaQ = (short*)alloc((size_t)DM * DM * 2);
  short* WtsaK = (short*)alloc((size_t)DM * DM * 2);
  short* WtsaV = (short*)alloc((size_t)DM * DM * 2);
  short* WtsaO = (short*)alloc((size_t)DM * DM * 2);
  short* Wtcaq = (short*)alloc((size_t)CAI * DM * 2);
  short* Wtk = (short*)alloc((size_t)CAI * DM * 2);
  short* Wtv = (short*)alloc((size_t)CAI * DM * 2);
  short* Wtcao = (short*)alloc((size_t)DM * CAI * 2);
  short* Wtf1 = (short*)alloc((size_t)DFFN * DM * 2);
  short* Wtf2 = (short*)alloc((size_t)DM * DFFN * 2);
  short* abuf = (short*)alloc((size_t)MV * DM * 2);  // bf16 A for big GEMMs
  if ((size_t)(w - (char*)d_ws) > ws_size) return;  // graceful fail (diagnostic)

  // SA-phase overlays in region0
  float* qh_sa = (float*)(r0 + 0 * MB);
  float* kh_sa = (float*)(r0 + 4 * MB);
  float* vh_sa = (float*)(r0 + 8 * MB);
  float* sa_att = (float*)(r0 + 12 * MB);
  float* sa_proj = (float*)(r0 + 16 * MB);
  float* o_p0 = (float*)(r0 + 20 * MB);   // 4 MB unnormalized partial O (half 0)
  float* o_p1 = (float*)(r0 + 24 * MB);   // 4 MB (half 1)
  float* mlb = (float*)(r0 + 28 * MB);    // 2 x 32768 x 2 f32 = 512 KB
  // CA volume overlay
  bf16* vol = (bf16*)r0;  // 64 MB
  // post-CA overlays
  float* ca_o = (float*)(r0 + 0 * MB);
  float* x2_f = (float*)(r0 + 4 * MB);
  float* ffn_h = (float*)(r0 + 8 * MB);   // 16 MB
  float* ffn_o = (float*)(r0 + 24 * MB);

  const int n4v = MV * DM / 4;  // prep float4 count

  dim3 blk(256);
  // --- weight transposes (bf16 cast) ---
  wtrans_k<8><<<dim3(DM * DM / 256), blk, 0, stream>>>(sa_Wq, WtsaQ, DM);
  wtrans_k<8><<<dim3(DM * DM / 256), blk, 0, stream>>>(sa_Wk, WtsaK, DM);
  wtrans_k<8><<<dim3(DM * DM / 256), blk, 0, stream>>>(sa_Wv, WtsaV, DM);
  wtrans_k<8><<<dim3(DM * DM / 256), blk, 0, stream>>>(sa_Wo, WtsaO, DM);
  wtrans_k<8><<<dim3(DM * CAI / 256), blk, 0, stream>>>(ca_Wq, Wtcaq, CAI);
  wtrans_k<8><<<dim3(DM * CAI / 256), blk, 0, stream>>>(ca_Wk, Wtk, CAI);
  wtrans_k<8><<<dim3(DM * CAI / 256), blk, 0, stream>>>(ca_Wv, Wtv, CAI);
  wtrans_k<8><<<dim3(DM * DFFN / 256), blk, 0, stream>>>(ffn_W1, Wtf1, DFFN);
  wtrans_k<9><<<dim3(CAI * DM / 256), blk, 0, stream>>>(ca_Wo, Wtcao, DM);
  wtrans_k<10><<<dim3(DFFN * DM / 256), blk, 0, stream>>>(ffn_W2, Wtf2, DM);
  // --- self-attention ---
  mgemm_k<1, 0, 0><<<dim3(DM / 128, MQ / 128), blk, 0, stream>>>(query, qpos, WtsaQ, sa_bq, (void*)qh_sa, MQ, DM, DM);
  mgemm_k<1, 0, 0><<<dim3(DM / 128, MQ / 128), blk, 0, stream>>>(query, qpos, WtsaK, sa_bk, (void*)kh_sa, MQ, DM, DM);
  mgemm_k<0, 0, 0><<<dim3(DM / 128, MQ / 128), blk, 0, stream>>>(query, query, WtsaV, sa_bv, (void*)vh_sa, MQ, DM, DM);
  sa_flash_k<<<dim3(16, 8, 8), blk, 0, stream>>>(qh_sa, kh_sa, vh_sa, o_p0, o_p1, mlb);
  sa_merge_k<<<dim3(4096), blk, 0, stream>>>(o_p0, o_p1, mlb, sa_att);
  mgemm_k<0, 0, 0><<<dim3(DM / 128, MQ / 128), blk, 0, stream>>>(sa_att, sa_att, WtsaO, sa_bo, (void*)sa_proj, MQ, DM, DM);
  ln_k<<<dim3(MQ / 4), blk, 0, stream>>>(query, sa_proj, ln1_g, ln1_b, x1_f);
  // --- deformable cross-attention (single shared volume buffer) ---
  mgemm_k<0, 0, 0><<<dim3(CAI / 128, MQ / 128), blk, 0, stream>>>(x1_f, x1_f, Wtcaq, ca_bq, (void*)ca_qh, MQ, CAI, DM);
  refoff_k<<<dim3(MQ), dim3(128), 0, stream>>>(x1_f, ca_Wref, ca_bref, ca_Woff, ca_boff, refb, offb);
  prep_k<1><<<dim3(2048), blk, 0, stream>>>(pos, img, abuf, n4v);
  bgemm_k<<<dim3(CAI / 128, MV / 128), blk, 0, stream>>>(abuf, Wtk, ca_bk, vol, MV, CAI, DM);
  ca_logits_k<<<dim3(8192), blk, 0, stream>>>(ca_qh, refb, offb, vol, logits, 0);
  prep_k<1><<<dim3(2048), blk, 0, stream>>>(pos, flow, abuf, n4v);
  bgemm_k<<<dim3(CAI / 128, MV / 128), blk, 0, stream>>>(abuf, Wtk, ca_bk, vol, MV, CAI, DM);
  ca_logits_k<<<dim3(8192), blk, 0, stream>>>(ca_qh, refb, offb, vol, logits, 4);
  ca_softmax_k<<<dim3(128), blk, 0, stream>>>(logits);
  prep_k<0><<<dim3(2048), blk, 0, stream>>>(img, img, abuf, n4v);
  bgemm_k<<<dim3(CAI / 128, MV / 128), blk, 0, stream>>>(abuf, Wtv, ca_bv, vol, MV, CAI, DM);
  ca_acc_k<1><<<dim3(8192), blk, 0, stream>>>(refb, offb, vol, logits, ca_acc, 0);
  prep_k<0><<<dim3(2048), blk, 0, stream>>>(flow, flow, abuf, n4v);
  bgemm_k<<<dim3(CAI / 128, MV / 128), blk, 0, stream>>>(abuf, Wtv, ca_bv, vol, MV, CAI, DM);
  ca_acc_k<0><<<dim3(8192), blk, 0, stream>>>(refb, offb, vol, logits, ca_acc, 4);
  mgemm_k<0, 0, 0><<<dim3(DM / 128, MQ / 128), blk, 0, stream>>>(ca_acc, ca_acc, Wtcao, ca_bo, (void*)ca_o, MQ, DM, CAI);
  ln_k<<<dim3(MQ / 4), blk, 0, stream>>>(x1_f, ca_o, ln2_g, ln2_b, x2_f);
  // --- FFN ---
  mgemm_k<0, 1, 0><<<dim3(DFFN / 128, MQ / 128), blk, 0, stream>>>(x2_f, x2_f, Wtf1, ffn_b1, (void*)ffn_h, MQ, DFFN, DM);
  mgemm_k<0, 0, 0><<<dim3(DM / 128, MQ / 128), blk, 0, stream>>>(ffn_h, ffn_h, Wtf2, ffn_b2, (void*)ffn_o, MQ, DM, DFFN);
  ln_k<<<dim3(MQ / 4), blk, 0, stream>>>(x2_f, ffn_o, ln3_g, ln3_b, (float*)d_out);
}

// Round 7
// 725.996 us; speedup vs baseline: 1.0109x; 1.0109x over previous
//
#include <hip/hip_runtime.h>
#include <hip/hip_bf16.h>

#define BQ 4
#define NQT 1024
#define DM 256
#define HSA 8
#define DHSA 32
#define CAH 8
#define CADH 64
#define CAI 512
#define NPT 4
#define DFFN 1024
#define TT 4
#define HH 64
#define WW 64
#define LVOL 16384

using bf16 = __hip_bfloat16;
typedef __attribute__((ext_vector_type(4))) float fx4;
typedef __attribute__((ext_vector_type(8))) short s8v;
typedef __attribute__((ext_vector_type(4))) short s4v;

__device__ __forceinline__ float b2f(bf16 v) { return __bfloat162float(v); }
__device__ __forceinline__ bf16  f2b(float v) { return __float2bfloat16(v); }
__device__ __forceinline__ short f2bs(float v) {
  bf16 b = __float2bfloat16(v);
  return *reinterpret_cast<short*>(&b);
}

__device__ __forceinline__ float wave_sum64(float v) {
#pragma unroll
  for (int o = 32; o >= 1; o >>= 1) v += __shfl_xor(v, o, 64);
  return v;
}

__device__ __forceinline__ s8v pack8(float4 a, float4 b) {
  return (s8v){f2bs(a.x), f2bs(a.y), f2bs(a.z), f2bs(a.w),
               f2bs(b.x), f2bs(b.y), f2bs(b.z), f2bs(b.w)};
}

// async global->LDS, 16B per lane; lds base must be wave-uniform.
__device__ __forceinline__ void gl_lds16(const void* g, void* l) {
  __builtin_amdgcn_global_load_lds(
      (const __attribute__((address_space(1))) unsigned int*)g,
      (__attribute__((address_space(3))) unsigned int*)l, 16, 0, 0);
}

// ---------------------------------------------------------------------------
// Weight pre-transpose + bf16 cast: W[K][N] f32 -> Wt[N][K] bf16.
// ---------------------------------------------------------------------------
template <int KSH>
__global__ __launch_bounds__(256) void wtrans_k(const float* __restrict__ W,
                                               short* __restrict__ Wt, int N) {
  const int i = blockIdx.x * 256 + threadIdx.x;  // i = n*K + k
  const int k = i & ((1 << KSH) - 1);
  const int n = i >> KSH;
  Wt[i] = f2bs(W[(size_t)k * N + n]);
}

// ---------------------------------------------------------------------------
// Elementwise prep: O = bf16(A (+B)). 4x unroll; ALL loads issued before a
// sched_barrier(0), dependent convert/stores after. R6 postmortem: without
// the fence the compiler reg-allocated to 28 VGPR = 2 loads in flight
// (latency-bound at ~1.7 TB/s HBM). Fence forces ~8 KB/wave in flight.
// ---------------------------------------------------------------------------
template <int DUAL>
__global__ __launch_bounds__(256) void prep_k(const float* __restrict__ A,
                                              const float* __restrict__ B,
                                              short* __restrict__ O, int n4) {
  const int tot = gridDim.x * 256;
  int i = blockIdx.x * 256 + threadIdx.x;
  for (; i + 3 * tot < n4; i += 4 * tot) {
    const int i0 = i, i1 = i + tot, i2 = i + 2 * tot, i3 = i + 3 * tot;
    float4 a0 = ((const float4*)A)[i0];
    float4 a1 = ((const float4*)A)[i1];
    float4 a2 = ((const float4*)A)[i2];
    float4 a3 = ((const float4*)A)[i3];
    float4 b0, b1, b2, b3;
    if (DUAL) {
      b0 = ((const float4*)B)[i0];
      b1 = ((const float4*)B)[i1];
      b2 = ((const float4*)B)[i2];
      b3 = ((const float4*)B)[i3];
    }
    __builtin_amdgcn_sched_barrier(0);  // keep ALL loads issued & live
    if (DUAL) {
      a0.x += b0.x; a0.y += b0.y; a0.z += b0.z; a0.w += b0.w;
      a1.x += b1.x; a1.y += b1.y; a1.z += b1.z; a1.w += b1.w;
      a2.x += b2.x; a2.y += b2.y; a2.z += b2.z; a2.w += b2.w;
      a3.x += b3.x; a3.y += b3.y; a3.z += b3.z; a3.w += b3.w;
    }
    ((s4v*)O)[i0] = (s4v){f2bs(a0.x), f2bs(a0.y), f2bs(a0.z), f2bs(a0.w)};
    ((s4v*)O)[i1] = (s4v){f2bs(a1.x), f2bs(a1.y), f2bs(a1.z), f2bs(a1.w)};
    ((s4v*)O)[i2] = (s4v){f2bs(a2.x), f2bs(a2.y), f2bs(a2.z), f2bs(a2.w)};
    ((s4v*)O)[i3] = (s4v){f2bs(a3.x), f2bs(a3.y), f2bs(a3.z), f2bs(a3.w)};
  }
  for (; i < n4; i += tot) {
    float4 a = ((const float4*)A)[i];
    if (DUAL) {
      const float4 b = ((const float4*)B)[i];
      a.x += b.x; a.y += b.y; a.z += b.z; a.w += b.w;
    }
    ((s4v*)O)[i] = (s4v){f2bs(a.x), f2bs(a.y), f2bs(a.z), f2bs(a.w)};
  }
}

// ---------------------------------------------------------------------------
// bf16 MFMA GEMM (m97-structure): C[M,N] = A[M,K](bf16) @ Wt[N,K](bf16) + b.
// 128x128 tile, BK=32, 256 threads = 4 waves; global_load_lds width=16,
// double-buffered, one barrier per K-step. XCD swizzle (T1). Output bf16.
// ---------------------------------------------------------------------------
__global__ __launch_bounds__(256) void bgemm_k(
    const short* __restrict__ A, const short* __restrict__ Wt,
    const float* __restrict__ bias, bf16* __restrict__ Cout,
    int M, int N, int K) {
  __shared__ short As[2][128 * 32];  // [m][k] linear (gl_lds layout)
  __shared__ short Bs[2][128 * 32];  // [n][k] linear
  const int tid = threadIdx.x;
  const int lane = tid & 63, w = tid >> 6;
  const int wr = w >> 1, wc = w & 1;
  const int lm = lane & 15, quad = lane >> 4;
  const int nwg = gridDim.x * gridDim.y;
  const int ib = blockIdx.y * gridDim.x + blockIdx.x;
  const int id = (ib & 7) * (nwg >> 3) + (ib >> 3);
  const int m0 = (id / gridDim.x) * 128;
  const int n0 = (id % gridDim.x) * 128;

  const int srow = lane >> 2;        // 0..15 within 16-row chunk
  const int scol = (lane & 3) * 8;   // k-chunk of 8 shorts (16 B)
  const size_t arow = (size_t)(m0 + w * 32 + srow);
  const size_t brow = (size_t)(n0 + w * 32 + srow);

  fx4 acc[4][4] = {};
  const int nt = K / 32;
  int cur = 0;
  {
    gl_lds16(&A[arow * K + scol], &As[0][(w * 32) * 32]);
    gl_lds16(&A[(arow + 16) * K + scol], &As[0][(w * 32 + 16) * 32]);
    gl_lds16(&Wt[brow * K + scol], &Bs[0][(w * 32) * 32]);
    gl_lds16(&Wt[(brow + 16) * K + scol], &Bs[0][(w * 32 + 16) * 32]);
  }
  __syncthreads();
  for (int t = 0; t < nt; t++) {
    if (t + 1 < nt) {
      const int k0 = (t + 1) * 32;
      gl_lds16(&A[arow * K + k0 + scol], &As[cur ^ 1][(w * 32) * 32]);
      gl_lds16(&A[(arow + 16) * K + k0 + scol], &As[cur ^ 1][(w * 32 + 16) * 32]);
      gl_lds16(&Wt[brow * K + k0 + scol], &Bs[cur ^ 1][(w * 32) * 32]);
      gl_lds16(&Wt[(brow + 16) * K + k0 + scol], &Bs[cur ^ 1][(w * 32 + 16) * 32]);
    }
    s8v af[4], bfr[4];
#pragma unroll
    for (int f = 0; f < 4; f++) {
      af[f] = *(s8v*)&As[cur][(wr * 64 + f * 16 + lm) * 32 + quad * 8];
      bfr[f] = *(s8v*)&Bs[cur][(wc * 64 + f * 16 + lm) * 32 + quad * 8];
    }
#pragma unroll
    for (int fm = 0; fm < 4; fm++)
#pragma unroll
      for (int fn = 0; fn < 4; fn++)
        acc[fm][fn] = __builtin_amdgcn_mfma_f32_16x16x32_bf16(
            af[fm], bfr[fn], acc[fm][fn], 0, 0, 0);
    __syncthreads();
    cur ^= 1;
  }
#pragma unroll
  for (int fn = 0; fn < 4; fn++) {
    const int n = n0 + wc * 64 + fn * 16 + lm;
    const float bb = bias[n];
#pragma unroll
    for (int fm = 0; fm < 4; fm++) {
      const int mbase = m0 + wr * 64 + fm * 16 + quad * 4;
#pragma unroll
      for (int r = 0; r < 4; r++)
        Cout[(size_t)(mbase + r) * N + n] = f2b(acc[fm][fn][r] + bb);
    }
  }
}

// ---------------------------------------------------------------------------
// MFMA GEMM (R2 version): C[M,N] = (A (+A2))[M,K] @ W[K,N] + bias.
// ---------------------------------------------------------------------------
template <int DUAL, int RELU, int OUTBF>
__global__ __launch_bounds__(256) void mgemm_k(
    const float* __restrict__ A, const float* __restrict__ A2,
    const short* __restrict__ Wt, const float* __restrict__ bias,
    void* __restrict__ Cout, int M, int N, int K) {
  __shared__ short As[2][128 * 40];
  __shared__ short Bs[2][128 * 40];
  const int tid = threadIdx.x;
  const int lane = tid & 63, w = tid >> 6;
  const int wr = w >> 1, wc = w & 1;
  const int lm = lane & 15, quad = lane >> 4;
  const int nwg = gridDim.x * gridDim.y;
  const int ib = blockIdx.y * gridDim.x + blockIdx.x;
  const int id = (ib & 7) * (nwg >> 3) + (ib >> 3);
  const int m0 = (id / gridDim.x) * 128;
  const int n0 = (id % gridDim.x) * 128;

  const int am = tid >> 3, ak = (tid & 7) * 4;

  float4 pa[4], pa2[4];
  s8v pb[2];
  auto loadT = [&](int k0) {
#pragma unroll
    for (int i = 0; i < 4; i++) {
      pa[i] = *(const float4*)&A[(size_t)(m0 + am + i * 32) * K + k0 + ak];
      if (DUAL)
        pa2[i] = *(const float4*)&A2[(size_t)(m0 + am + i * 32) * K + k0 + ak];
    }
#pragma unroll
    for (int i = 0; i < 2; i++) {
      int unit = tid + i * 256;
      pb[i] = *(const s8v*)&Wt[(size_t)(n0 + (unit >> 2)) * K + k0 +
                               (unit & 3) * 8];
    }
  };
  auto stageT = [&](int buf) {
#pragma unroll
    for (int i = 0; i < 4; i++) {
      float x0 = pa[i].x, x1 = pa[i].y, x2 = pa[i].z, x3 = pa[i].w;
      if (DUAL) { x0 += pa2[i].x; x1 += pa2[i].y; x2 += pa2[i].z; x3 += pa2[i].w; }
      s4v sv = {f2bs(x0), f2bs(x1), f2bs(x2), f2bs(x3)};
      *(s4v*)&As[buf][(am + i * 32) * 40 + ak] = sv;
    }
#pragma unroll
    for (int i = 0; i < 2; i++) {
      int unit = tid + i * 256;
      *(s8v*)&Bs[buf][(unit >> 2) * 40 + (unit & 3) * 8] = pb[i];
    }
  };

  fx4 acc[4][4] = {};
  loadT(0);
  stageT(0);
  __syncthreads();
  int cur = 0;
  for (int k0 = 0; k0 < K; k0 += 32) {
    const int more = (k0 + 32 < K);
    if (more) loadT(k0 + 32);
    s8v af[4], bfr[4];
#pragma unroll
    for (int f = 0; f < 4; f++) {
      af[f] = *(s8v*)&As[cur][(wr * 64 + f * 16 + lm) * 40 + quad * 8];
      bfr[f] = *(s8v*)&Bs[cur][(wc * 64 + f * 16 + lm) * 40 + quad * 8];
    }
#pragma unroll
    for (int fm = 0; fm < 4; fm++)
#pragma unroll
      for (int fn = 0; fn < 4; fn++)
        acc[fm][fn] = __builtin_amdgcn_mfma_f32_16x16x32_bf16(
            af[fm], bfr[fn], acc[fm][fn], 0, 0, 0);
    if (more) stageT(cur ^ 1);
    __syncthreads();
    cur ^= 1;
  }
#pragma unroll
  for (int fn = 0; fn < 4; fn++) {
    const int n = n0 + wc * 64 + fn * 16 + lm;
    const float bb = bias[n];
#pragma unroll
    for (int fm = 0; fm < 4; fm++) {
      const int mbase = m0 + wr * 64 + fm * 16 + quad * 4;
#pragma unroll
      for (int r = 0; r < 4; r++) {
        float v = acc[fm][fn][r] + bb;
        if (RELU) v = fmaxf(v, 0.0f);
        const size_t off = (size_t)(mbase + r) * N + n;
        if (OUTBF)
          ((bf16*)Cout)[off] = f2b(v);
        else
          ((float*)Cout)[off] = v;
      }
    }
  }
}

// ---------------------------------------------------------------------------
// Flash-style MFMA self-attention, KV-split by 2 (flash-decoding).
// ---------------------------------------------------------------------------
__global__ __launch_bounds__(256) void sa_flash_k(
    const float* __restrict__ qh, const float* __restrict__ kh,
    const float* __restrict__ vh, float* __restrict__ op0,
    float* __restrict__ op1, float* __restrict__ mlb) {
  __shared__ short Ks[64 * 72];
  __shared__ short Vt[32 * 72];
  __shared__ short Ps[64 * 72];
  const int qt = blockIdx.x, h = blockIdx.y;
  const int b = blockIdx.z >> 1, half = blockIdx.z & 1;
  const int tid = threadIdx.x;
  const int w = tid >> 6, lane = tid & 63;
  const int lm = lane & 15, quad = lane >> 4;
  const size_t rowbase = (size_t)(b * NQT) * DM + h * DHSA;
  float* __restrict__ opart = half ? op1 : op0;
  float* __restrict__ ml = mlb + (size_t)half * (32768 * 2);

  s8v aq;
  {
    const int qrow = qt * 64 + w * 16 + lm;
    const float* qp = &qh[rowbase + (size_t)qrow * DM + quad * 8];
    const float4 q0 = *(const float4*)qp;
    const float4 q1 = *(const float4*)(qp + 4);
    const float sc = 0.17677669529663687f;
    aq = (s8v){f2bs(q0.x * sc), f2bs(q0.y * sc), f2bs(q0.z * sc), f2bs(q0.w * sc),
               f2bs(q1.x * sc), f2bs(q1.y * sc), f2bs(q1.z * sc), f2bs(q1.w * sc)};
  }

  fx4 o0 = {}, o1 = {};
  float mrun[4] = {-1e30f, -1e30f, -1e30f, -1e30f};
  float lrun[4] = {0.f, 0.f, 0.f, 0.f};
  const int jr = tid >> 2;
  const int d0 = (tid & 3) * 8;

  for (int jt = half * 8; jt < half * 8 + 8; jt++) {
    __syncthreads();
    {
      const size_t rb = rowbase + (size_t)(jt * 64 + jr) * DM + d0;
      const float4 k0 = *(const float4*)&kh[rb];
      const float4 k1 = *(const float4*)&kh[rb + 4];
      *(s8v*)&Ks[jr * 72 + d0] = pack8(k0, k1);
      const float4 v0 = *(const float4*)&vh[rb];
      const float4 v1 = *(const float4*)&vh[rb + 4];
      Vt[(d0 + 0) * 72 + jr] = f2bs(v0.x);
      Vt[(d0 + 1) * 72 + jr] = f2bs(v0.y);
      Vt[(d0 + 2) * 72 + jr] = f2bs(v0.z);
      Vt[(d0 + 3) * 72 + jr] = f2bs(v0.w);
      Vt[(d0 + 4) * 72 + jr] = f2bs(v1.x);
      Vt[(d0 + 5) * 72 + jr] = f2bs(v1.y);
      Vt[(d0 + 6) * 72 + jr] = f2bs(v1.z);
      Vt[(d0 + 7) * 72 + jr] = f2bs(v1.w);
    }
    __syncthreads();
    fx4 s[4];
    const fx4 zero = {};
#pragma unroll
    for (int nf = 0; nf < 4; nf++) {
      s8v kb = *(const s8v*)&Ks[(nf * 16 + lm) * 72 + quad * 8];
      s[nf] = __builtin_amdgcn_mfma_f32_16x16x32_bf16(aq, kb, zero, 0, 0, 0);
    }
#pragma unroll
    for (int r = 0; r < 4; r++) {
      float mx = fmaxf(fmaxf(s[0][r], s[1][r]), fmaxf(s[2][r], s[3][r]));
#pragma unroll
      for (int off = 8; off >= 1; off >>= 1)
        mx = fmaxf(mx, __shfl_xor(mx, off, 64));
      const float mnew = fmaxf(mrun[r], mx);
      const float corr = expf(mrun[r] - mnew);
      mrun[r] = mnew;
      float p0 = expf(s[0][r] - mnew);
      float p1 = expf(s[1][r] - mnew);
      float p2 = expf(s[2][r] - mnew);
      float p3 = expf(s[3][r] - mnew);
      float rs = p0 + p1 + p2 + p3;
#pragma unroll
      for (int off = 8; off >= 1; off >>= 1) rs += __shfl_xor(rs, off, 64);
      lrun[r] = lrun[r] * corr + rs;
      o0[r] *= corr;
      o1[r] *= corr;
      s[0][r] = p0; s[1][r] = p1; s[2][r] = p2; s[3][r] = p3;
    }
#pragma unroll
    for (int nf = 0; nf < 4; nf++)
#pragma unroll
      for (int r = 0; r < 4; r++)
        Ps[(w * 16 + quad * 4 + r) * 72 + nf * 16 + lm] = f2bs(s[nf][r]);
#pragma unroll
    for (int ks = 0; ks < 2; ks++) {
      s8v pf = *(const s8v*)&Ps[(w * 16 + lm) * 72 + ks * 32 + quad * 8];
      s8v vb0 = *(const s8v*)&Vt[lm * 72 + ks * 32 + quad * 8];
      s8v vb1 = *(const s8v*)&Vt[(16 + lm) * 72 + ks * 32 + quad * 8];
      o0 = __builtin_amdgcn_mfma_f32_16x16x32_bf16(pf, vb0, o0, 0, 0, 0);
      o1 = __builtin_amdgcn_mfma_f32_16x16x32_bf16(pf, vb1, o1, 0, 0, 0);
    }
  }
#pragma unroll
  for (int r = 0; r < 4; r++) {
    const int row = qt * 64 + w * 16 + quad * 4 + r;
    const size_t base = rowbase + (size_t)row * DM;
    opart[base + lm] = o0[r];
    opart[base + 16 + lm] = o1[r];
    if (lm == 0) {
      const int rowid = (b * 8 + h) * 1024 + row;
      ml[(size_t)rowid * 2] = mrun[r];
      ml[(size_t)rowid * 2 + 1] = lrun[r];
    }
  }
}

// Merge the two KV-halves: out = (o0*w0 + o1*w1) / (l0*w0 + l1*w1).
__global__ __launch_bounds__(256) void sa_merge_k(
    const float* __restrict__ op0, const float* __restrict__ op1,
    const float* __restrict__ mlb, float* __restrict__ outp) {
  const int t = blockIdx.x * 256 + threadIdx.x;  // 0..1048575
  const int d = t & 31;
  const int rowid = t >> 5;  // (b*8+h)*1024 + n
  const int n = rowid & 1023, h = (rowid >> 10) & 7, b = rowid >> 13;
  const size_t addr = ((size_t)(b * NQT + n)) * DM + h * DHSA + d;
  const float m0 = mlb[(size_t)rowid * 2], l0 = mlb[(size_t)rowid * 2 + 1];
  const float m1 = mlb[65536 + (size_t)rowid * 2];
  const float l1 = mlb[65536 + (size_t)rowid * 2 + 1];
  const float M = fmaxf(m0, m1);
  const float w0 = expf(m0 - M), w1 = expf(m1 - M);
  const float inv = 1.0f / (l0 * w0 + l1 * w1);
  outp[addr] = (op0[addr] * w0 + op1[addr] * w1) * inv;
}

// ---------------------------------------------------------------------------
// ref = sigmoid(x1 @ Wref + bref), off = x1 @ Woff + boff  (per query row)
// ---------------------------------------------------------------------------
__global__ __launch_bounds__(128) void refoff_k(
    const float* __restrict__ x1, const float* __restrict__ Wref,
    const float* __restrict__ bref, const float* __restrict__ Woff,
    const float* __restrict__ boff, float* __restrict__ refb,
    float* __restrict__ offb) {
  __shared__ float xs[256];
  const int row = blockIdx.x;
  const int tid = threadIdx.x;
  xs[tid] = x1[(size_t)row * DM + tid];
  xs[tid + 128] = x1[(size_t)row * DM + tid + 128];
  __syncthreads();
  if (tid < 3) {
    float s = bref[tid];
    for (int d = 0; d < 256; d++) s = fmaf(xs[d], Wref[d * 3 + tid], s);
    refb[(size_t)row * 3 + tid] = 1.0f / (1.0f + expf(-s));
  } else if (tid < 99) {
    int o = tid - 3;
    float s = boff[o];
    for (int d = 0; d < 256; d++) s = fmaf(xs[d], Woff[d * 96 + o], s);
    offb[(size_t)row * 96 + o] = s;
  }
}

// ---------------------------------------------------------------------------
// Shared trilinear corner computation for one (bn, h).
// ---------------------------------------------------------------------------
__device__ __forceinline__ void calc_corners(
    const float* __restrict__ refb, const float* __restrict__ offb, int bn,
    int h, int (&idxs)[NPT][8], float (&wts)[NPT][8]) {
  const float rt = refb[bn * 3 + 0], ry = refb[bn * 3 + 1], rx = refb[bn * 3 + 2];
  const float* ofp = &offb[(size_t)bn * 96 + h * 12];
#pragma unroll
  for (int p = 0; p < NPT; p++) {
    float lt = rt + ofp[p * 3 + 0] * 0.5f;      // OFFSET_SCALE / T
    float ly = ry + ofp[p * 3 + 1] * 0.03125f;  // OFFSET_SCALE / H
    float lx = rx + ofp[p * 3 + 2] * 0.03125f;  // OFFSET_SCALE / W
    float pt = fminf(fmaxf(lt, 0.f), 1.f) * (TT - 1);
    float py = fminf(fmaxf(ly, 0.f), 1.f) * (HH - 1);
    float px = fminf(fmaxf(lx, 0.f), 1.f) * (WW - 1);
    float f0t = floorf(pt), f0y = floorf(py), f0x = floorf(px);
    float frt = pt - f0t, fry = py - f0y, frx = px - f0x;
    int t0 = (int)f0t, y0 = (int)f0y, x0 = (int)f0x;
    int t1 = min(t0 + 1, TT - 1), y1 = min(y0 + 1, HH - 1), x1 = min(x0 + 1, WW - 1);
    float wt0 = 1.f - frt, wy0 = 1.f - fry, wx0 = 1.f - frx;
#pragma unroll
    for (int c = 0; c < 8; c++) {
      int dt = c >> 2, dy = (c >> 1) & 1, dx = c & 1;
      int ct = dt ? t1 : t0, cy = dy ? y1 : y0, cx = dx ? x1 : x0;
      idxs[p][c] = ct * (HH * WW) + cy * WW + cx;
      wts[p][c] = (dt ? frt : wt0) * (dy ? fry : wy0) * (dx ? frx : wx0);
    }
  }
}

// ---------------------------------------------------------------------------
// Sample k-volume at the 4 points, dot with q -> 4 logits into slots.
// ---------------------------------------------------------------------------
__global__ __launch_bounds__(256) void ca_logits_k(
    const float* __restrict__ qh, const float* __restrict__ refb,
    const float* __restrict__ offb, const bf16* __restrict__ vol,
    float* __restrict__ logits, int slot) {
  const int wid = (blockIdx.x * blockDim.x + threadIdx.x) >> 6;  // 0..32767
  const int lane = threadIdx.x & 63;
  const int h = wid & 7;
  const int bn = wid >> 3;  // 0..4095
  const int b = bn >> 10;
  const float q = qh[(size_t)bn * CAI + h * CADH + lane];
  int idxs[NPT][8];
  float wts[NPT][8];
  calc_corners(refb, offb, bn, h, idxs, wts);
  const size_t volbase = (size_t)b * LVOL * CAI + h * CADH + lane;
  float* lp = logits + ((size_t)bn * CAH + h) * 8 + slot;
#pragma unroll
  for (int p = 0; p < NPT; p++) {
    float ks = 0.f;
#pragma unroll
    for (int c = 0; c < 8; c++)
      ks = fmaf(wts[p][c], b2f(vol[volbase + (size_t)idxs[p][c] * CAI]), ks);
    float li = wave_sum64(q * ks) * 0.125f;  // 1/sqrt(64)
    if (lane == p) lp[p] = li;
  }
}

// ---------------------------------------------------------------------------
// Joint softmax over the 8 logits (4 img + 4 flow) per (bn, h), in place.
// ---------------------------------------------------------------------------
__global__ __launch_bounds__(256) void ca_softmax_k(float* __restrict__ logits) {
  const int i = blockIdx.x * blockDim.x + threadIdx.x;  // 0..32767
  float* p = logits + (size_t)i * 8;
  float v[8], m = -1e30f;
#pragma unroll
  for (int j = 0; j < 8; j++) { v[j] = p[j]; m = fmaxf(m, v[j]); }
  float s = 0.f;
#pragma unroll
  for (int j = 0; j < 8; j++) { v[j] = expf(v[j] - m); s += v[j]; }
  const float inv = 1.0f / s;
#pragma unroll
  for (int j = 0; j < 8; j++) p[j] = v[j] * inv;
}

// ---------------------------------------------------------------------------
// Sample v-volume, weight by attn slots, accumulate into f32 acc.
// ---------------------------------------------------------------------------
template <int FIRST>
__global__ __launch_bounds__(256) void ca_acc_k(
    const float* __restrict__ refb, const float* __restrict__ offb,
    const bf16* __restrict__ vol, const float* __restrict__ attn,
    float* __restrict__ acc, int slot) {
  const int wid = (blockIdx.x * blockDim.x + threadIdx.x) >> 6;
  const int lane = threadIdx.x & 63;
  const int h = wid & 7;
  const int bn = wid >> 3;
  const int b = bn >> 10;
  int idxs[NPT][8];
  float wts[NPT][8];
  calc_corners(refb, offb, bn, h, idxs, wts);
  const size_t volbase = (size_t)b * LVOL * CAI + h * CADH + lane;
  const float* ap = attn + ((size_t)bn * CAH + h) * 8 + slot;
  const size_t off = (size_t)bn * CAI + h * CADH + lane;
  float a = FIRST ? 0.f : acc[off];
#pragma unroll
  for (int p = 0; p < NPT; p++) {
    float vs = 0.f;
#pragma unroll
    for (int c = 0; c < 8; c++)
      vs = fmaf(wts[p][c], b2f(vol[volbase + (size_t)idxs[p][c] * CAI]), vs);
    a = fmaf(ap[p], vs, a);
  }
  acc[off] = a;
}

// ---------------------------------------------------------------------------
// LayerNorm over 256 dims of (res + x); one wave per row; f32 in/out.
// ---------------------------------------------------------------------------
__global__ __launch_bounds__(256) void ln_k(
    const float* __restrict__ resv, const float* __restrict__ x,
    const float* __restrict__ g, const float* __restrict__ bb,
    float* __restrict__ of) {
  const int row = (blockIdx.x * blockDim.x + threadIdx.x) >> 6;
  const int lane = threadIdx.x & 63;
  const size_t base = (size_t)row * DM;
  float v[4];
#pragma unroll
  for (int i = 0; i < 4; i++) {
    int d = lane + i * 64;
    v[i] = resv[base + d] + x[base + d];
  }
  float s = wave_sum64(v[0] + v[1] + v[2] + v[3]);
  const float mean = s * (1.0f / 256.0f);
  float vs = 0.f;
#pragma unroll
  for (int i = 0; i < 4; i++) { float d0 = v[i] - mean; vs = fmaf(d0, d0, vs); }
  vs = wave_sum64(vs);
  const float rstd = rsqrtf(vs * (1.0f / 256.0f) + 1e-5f);
#pragma unroll
  for (int i = 0; i < 4; i++) {
    int d = lane + i * 64;
    of[base + d] = (v[i] - mean) * rstd * g[d] + bb[d];
  }
}

extern "C" void kernel_launch(void* const* d_in, const int* in_sizes, int n_in,
                              void* d_out, int out_size, void* d_ws,
                              size_t ws_size, hipStream_t stream) {
  const float* query = (const float*)d_in[0];
  const float* qpos = (const float*)d_in[1];
  const float* img = (const float*)d_in[2];
  const float* flow = (const float*)d_in[3];
  const float* pos = (const float*)d_in[4];
  const float* sa_Wq = (const float*)d_in[6];
  const float* sa_Wk = (const float*)d_in[7];
  const float* sa_Wv = (const float*)d_in[8];
  const float* sa_Wo = (const float*)d_in[9];
  const float* sa_bq = (const float*)d_in[10];
  const float* sa_bk = (const float*)d_in[11];
  const float* sa_bv = (const float*)d_in[12];
  const float* sa_bo = (const float*)d_in[13];
  const float* ln1_b = (const float*)d_in[14];
  const float* ln2_b = (const float*)d_in[15];
  const float* ln3_b = (const float*)d_in[16];
  const float* ln1_g = (const float*)d_in[17];
  const float* ln2_g = (const float*)d_in[18];
  const float* ln3_g = (const float*)d_in[19];
  const float* ca_Wq = (const float*)d_in[20];
  const float* ca_bq = (const float*)d_in[21];
  const float* ca_Wk = (const float*)d_in[22];
  const float* ca_bk = (const float*)d_in[23];
  const float* ca_Wv = (const float*)d_in[24];
  const float* ca_bv = (const float*)d_in[25];
  const float* ca_Wref = (const float*)d_in[26];
  const float* ca_bref = (const float*)d_in[27];
  const float* ca_Woff = (const float*)d_in[28];
  const float* ca_boff = (const float*)d_in[29];
  const float* ca_Wo = (const float*)d_in[30];
  const float* ca_bo = (const float*)d_in[31];
  const float* ffn_W1 = (const float*)d_in[32];
  const float* ffn_b1 = (const float*)d_in[33];
  const float* ffn_W2 = (const float*)d_in[34];
  const float* ffn_b2 = (const float*)d_in[35];

  const int MQ = BQ * NQT;   // 4096
  const int MV = BQ * LVOL;  // 65536
  const size_t MB = 1024 * 1024;

  char* r0 = (char*)d_ws;  // 64 MB time-shared region
  char* w = r0 + 64 * MB;
  auto alloc = [&](size_t n) {
    char* p = w;
    w += (n + 255) & ~(size_t)255;
    return p;
  };
  float* x1_f = (float*)alloc((size_t)MQ * DM * 4);
  float* ca_qh = (float*)alloc((size_t)MQ * CAI * 4);
  float* refb = (float*)alloc((size_t)MQ * 3 * 4);
  float* offb = (float*)alloc((size_t)MQ * 96 * 4);
  float* logits = (float*)alloc((size_t)MQ * CAH * 8 * 4);
  float* ca_acc = (float*)alloc((size_t)MQ * CAI * 4);
  // transposed bf16 weights [N][K]
  short* WtsaQ = (short*)alloc((size_t)DM * DM * 2);
  short* WtsaK = (short*)alloc((size_t)DM * DM * 2);
  short* WtsaV = (short*)alloc((size_t)DM * DM * 2);
  short* WtsaO = (short*)alloc((size_t)DM * DM * 2);
  short* Wtcaq = (short*)alloc((size_t)CAI * DM * 2);
  short* Wtk = (short*)alloc((size_t)CAI * DM * 2);
  short* Wtv = (short*)alloc((size_t)CAI * DM * 2);
  short* Wtcao = (short*)alloc((size_t)DM * CAI * 2);
  short* Wtf1 = (short*)alloc((size_t)DFFN * DM * 2);
  short* Wtf2 = (short*)alloc((size_t)DM * DFFN * 2);
  short* abuf = (short*)alloc((size_t)MV * DM * 2);  // bf16 A for big GEMMs
  if ((size_t)(w - (char*)d_ws) > ws_size) return;  // graceful fail (diagnostic)

  // SA-phase overlays in region0
  float* qh_sa = (float*)(r0 + 0 * MB);
  float* kh_sa = (float*)(r0 + 4 * MB);
  float* vh_sa = (float*)(r0 + 8 * MB);
  float* sa_att = (float*)(r0 + 12 * MB);
  float* sa_proj = (float*)(r0 + 16 * MB);
  float* o_p0 = (float*)(r0 + 20 * MB);   // 4 MB unnormalized partial O (half 0)
  float* o_p1 = (float*)(r0 + 24 * MB);   // 4 MB (half 1)
  float* mlb = (float*)(r0 + 28 * MB);    // 2 x 32768 x 2 f32 = 512 KB
  // CA volume overlay
  bf16* vol = (bf16*)r0;  // 64 MB
  // post-CA overlays
  float* ca_o = (float*)(r0 + 0 * MB);
  float* x2_f = (float*)(r0 + 4 * MB);
  float* ffn_h = (float*)(r0 + 8 * MB);   // 16 MB
  float* ffn_o = (float*)(r0 + 24 * MB);

  const int n4v = MV * DM / 4;  // prep float4 count

  dim3 blk(256);
  // --- weight transposes (bf16 cast) ---
  wtrans_k<8><<<dim3(DM * DM / 256), blk, 0, stream>>>(sa_Wq, WtsaQ, DM);
  wtrans_k<8><<<dim3(DM * DM / 256), blk, 0, stream>>>(sa_Wk, WtsaK, DM);
  wtrans_k<8><<<dim3(DM * DM / 256), blk, 0, stream>>>(sa_Wv, WtsaV, DM);
  wtrans_k<8><<<dim3(DM * DM / 256), blk, 0, stream>>>(sa_Wo, WtsaO, DM);
  wtrans_k<8><<<dim3(DM * CAI / 256), blk, 0, stream>>>(ca_Wq, Wtcaq, CAI);
  wtrans_k<8><<<dim3(DM * CAI / 256), blk, 0, stream>>>(ca_Wk, Wtk, CAI);
  wtrans_k<8><<<dim3(DM * CAI / 256), blk, 0, stream>>>(ca_Wv, Wtv, CAI);
  wtrans_k<8><<<dim3(DM * DFFN / 256), blk, 0, stream>>>(ffn_W1, Wtf1, DFFN);
  wtrans_k<9><<<dim3(CAI * DM / 256), blk, 0, stream>>>(ca_Wo, Wtcao, DM);
  wtrans_k<10><<<dim3(DFFN * DM / 256), blk, 0, stream>>>(ffn_W2, Wtf2, DM);
  // --- self-attention ---
  mgemm_k<1, 0, 0><<<dim3(DM / 128, MQ / 128), blk, 0, stream>>>(query, qpos, WtsaQ, sa_bq, (void*)qh_sa, MQ, DM, DM);
  mgemm_k<1, 0, 0><<<dim3(DM / 128, MQ / 128), blk, 0, stream>>>(query, qpos, WtsaK, sa_bk, (void*)kh_sa, MQ, DM, DM);
  mgemm_k<0, 0, 0><<<dim3(DM / 128, MQ / 128), blk, 0, stream>>>(query, query, WtsaV, sa_bv, (void*)vh_sa, MQ, DM, DM);
  sa_flash_k<<<dim3(16, 8, 8), blk, 0, stream>>>(qh_sa, kh_sa, vh_sa, o_p0, o_p1, mlb);
  sa_merge_k<<<dim3(4096), blk, 0, stream>>>(o_p0, o_p1, mlb, sa_att);
  mgemm_k<0, 0, 0><<<dim3(DM / 128, MQ / 128), blk, 0, stream>>>(sa_att, sa_att, WtsaO, sa_bo, (void*)sa_proj, MQ, DM, DM);
  ln_k<<<dim3(MQ / 4), blk, 0, stream>>>(query, sa_proj, ln1_g, ln1_b, x1_f);
  // --- deformable cross-attention (single shared volume buffer) ---
  mgemm_k<0, 0, 0><<<dim3(CAI / 128, MQ / 128), blk, 0, stream>>>(x1_f, x1_f, Wtcaq, ca_bq, (void*)ca_qh, MQ, CAI, DM);
  refoff_k<<<dim3(MQ), dim3(128), 0, stream>>>(x1_f, ca_Wref, ca_bref, ca_Woff, ca_boff, refb, offb);
  prep_k<1><<<dim3(2048), blk, 0, stream>>>(pos, img, abuf, n4v);
  bgemm_k<<<dim3(CAI / 128, MV / 128), blk, 0, stream>>>(abuf, Wtk, ca_bk, vol, MV, CAI, DM);
  ca_logits_k<<<dim3(8192), blk, 0, stream>>>(ca_qh, refb, offb, vol, logits, 0);
  prep_k<1><<<dim3(2048), blk, 0, stream>>>(pos, flow, abuf, n4v);
  bgemm_k<<<dim3(CAI / 128, MV / 128), blk, 0, stream>>>(abuf, Wtk, ca_bk, vol, MV, CAI, DM);
  ca_logits_k<<<dim3(8192), blk, 0, stream>>>(ca_qh, refb, offb, vol, logits, 4);
  ca_softmax_k<<<dim3(128), blk, 0, stream>>>(logits);
  prep_k<0><<<dim3(2048), blk, 0, stream>>>(img, img, abuf, n4v);
  bgemm_k<<<dim3(CAI / 128, MV / 128), blk, 0, stream>>>(abuf, Wtv, ca_bv, vol, MV, CAI, DM);
  ca_acc_k<1><<<dim3(8192), blk, 0, stream>>>(refb, offb, vol, logits, ca_acc, 0);
  prep_k<0><<<dim3(2048), blk, 0, stream>>>(flow, flow, abuf, n4v);
  bgemm_k<<<dim3(CAI / 128, MV / 128), blk, 0, stream>>>(abuf, Wtv, ca_bv, vol, MV, CAI, DM);
  ca_acc_k<0><<<dim3(8192), blk, 0, stream>>>(refb, offb, vol, logits, ca_acc, 4);
  mgemm_k<0, 0, 0><<<dim3(DM / 128, MQ / 128), blk, 0, stream>>>(ca_acc, ca_acc, Wtcao, ca_bo, (void*)ca_o, MQ, DM, CAI);
  ln_k<<<dim3(MQ / 4), blk, 0, stream>>>(x1_f, ca_o, ln2_g, ln2_b, x2_f);
  // --- FFN ---
  mgemm_k<0, 1, 0><<<dim3(DFFN / 128, MQ / 128), blk, 0, stream>>>(x2_f, x2_f, Wtf1, ffn_b1, (void*)ffn_h, MQ, DFFN, DM);
  mgemm_k<0, 0, 0><<<dim3(DM / 128, MQ / 128), blk, 0, stream>>>(ffn_h, ffn_h, Wtf2, ffn_b2, (void*)ffn_o, MQ, DM, DFFN);
  ln_k<<<dim3(MQ / 4), blk, 0, stream>>>(x2_f, ffn_o, ln3_g, ln3_b, (float*)d_out);
}

// Round 8
// 698.644 us; speedup vs baseline: 1.0505x; 1.0391x over previous
//
#include <hip/hip_runtime.h>
#include <hip/hip_bf16.h>

#define BQ 4
#define NQT 1024
#define DM 256
#define HSA 8
#define DHSA 32
#define CAH 8
#define CADH 64
#define CAI 512
#define NPT 4
#define DFFN 1024
#define TT 4
#define HH 64
#define WW 64
#define LVOL 16384

using bf16 = __hip_bfloat16;
typedef __attribute__((ext_vector_type(4))) float fx4;
typedef __attribute__((ext_vector_type(8))) short s8v;
typedef __attribute__((ext_vector_type(4))) short s4v;

__device__ __forceinline__ float b2f(bf16 v) { return __bfloat162float(v); }
__device__ __forceinline__ bf16  f2b(float v) { return __float2bfloat16(v); }
__device__ __forceinline__ short f2bs(float v) {
  bf16 b = __float2bfloat16(v);
  return *reinterpret_cast<short*>(&b);
}

__device__ __forceinline__ float wave_sum64(float v) {
#pragma unroll
  for (int o = 32; o >= 1; o >>= 1) v += __shfl_xor(v, o, 64);
  return v;
}

__device__ __forceinline__ s8v pack8(float4 a, float4 b) {
  return (s8v){f2bs(a.x), f2bs(a.y), f2bs(a.z), f2bs(a.w),
               f2bs(b.x), f2bs(b.y), f2bs(b.z), f2bs(b.w)};
}

// async global->LDS, 16B per lane; lds base must be wave-uniform.
__device__ __forceinline__ void gl_lds16(const void* g, void* l) {
  __builtin_amdgcn_global_load_lds(
      (const __attribute__((address_space(1))) unsigned int*)g,
      (__attribute__((address_space(3))) unsigned int*)l, 16, 0, 0);
}

// ---------------------------------------------------------------------------
// All 10 weight pre-transposes (W[K][N] f32 -> Wt[N][K] bf16) in ONE launch.
// Segments by blockIdx range; each segment is one weight matrix.
// ---------------------------------------------------------------------------
struct WtransArgs {
  const float* W[10];
  short* Wt[10];
};
__global__ __launch_bounds__(256) void wtrans_all_k(WtransArgs a) {
  // starts (in blocks), ksh = log2(K), N per segment:
  // 0: sa_Wq   [256,256]  blocks 0..255
  // 1: sa_Wk              256..511
  // 2: sa_Wv              512..767
  // 3: sa_Wo              768..1023
  // 4: ca_Wq   [256,512]  1024..1535
  // 5: ca_Wk              1536..2047
  // 6: ca_Wv              2048..2559
  // 7: ffn_W1  [256,1024] 2560..3583
  // 8: ca_Wo   [512,256]  3584..4095
  // 9: ffn_W2  [1024,256] 4096..5119
  const int blk = blockIdx.x;
  int seg, start, ksh, N;
  if (blk < 1024)      { seg = blk >> 8; start = seg << 8; ksh = 8; N = 256; }
  else if (blk < 2560) { seg = 4 + ((blk - 1024) >> 9); start = 1024 + ((seg - 4) << 9); ksh = 8; N = 512; }
  else if (blk < 3584) { seg = 7; start = 2560; ksh = 8; N = 1024; }
  else if (blk < 4096) { seg = 8; start = 3584; ksh = 9; N = 256; }
  else                 { seg = 9; start = 4096; ksh = 10; N = 256; }
  const int i = (blk - start) * 256 + threadIdx.x;  // i = n*K + k
  const int k = i & ((1 << ksh) - 1);
  const int n = i >> ksh;
  a.Wt[seg][i] = f2bs(a.W[seg][(size_t)k * N + n]);
}

// ---------------------------------------------------------------------------
// Fused volume GEMM: C[M,N] = bf16( (A (+A2))[M,K] f32 ) @ Wt[N,K] + bias.
// Replaces prep_k + bgemm_k: A is read f32, added, cast during LDS staging
// (reg prefetch, R2-proven); B comes in via global_load_lds width=16.
// 128x128 tile, BK=32, 256 thr = 4 waves of 64x64. XCD swizzle. bf16 out.
// ---------------------------------------------------------------------------
template <int DUAL>
__global__ __launch_bounds__(256) void vgemm_k(
    const float* __restrict__ A, const float* __restrict__ A2,
    const short* __restrict__ Wt, const float* __restrict__ bias,
    bf16* __restrict__ Cout, int M, int N, int K) {
  __shared__ short As[2][128 * 40];  // [m][k] padded (reg-staged f32->bf16)
  __shared__ short Bs[2][128 * 32];  // [n][k] linear (gl_lds layout)
  const int tid = threadIdx.x;
  const int lane = tid & 63, w = tid >> 6;
  const int wr = w >> 1, wc = w & 1;
  const int lm = lane & 15, quad = lane >> 4;
  const int nwg = gridDim.x * gridDim.y;
  const int ib = blockIdx.y * gridDim.x + blockIdx.x;
  const int id = (ib & 7) * (nwg >> 3) + (ib >> 3);
  const int m0 = (id / gridDim.x) * 128;
  const int n0 = (id % gridDim.x) * 128;

  const int am = tid >> 3, ak = (tid & 7) * 4;  // A: rows am+i*32, 4 cols
  const size_t brow = (size_t)(n0 + w * 32 + (lane >> 2));
  const int bcol = (lane & 3) * 8;              // B gl_lds: 16B/lane

  float4 pa[4], pa2[4];
  auto loadA = [&](int k0) {
#pragma unroll
    for (int i = 0; i < 4; i++) {
      pa[i] = *(const float4*)&A[(size_t)(m0 + am + i * 32) * K + k0 + ak];
      if (DUAL)
        pa2[i] = *(const float4*)&A2[(size_t)(m0 + am + i * 32) * K + k0 + ak];
    }
  };
  auto glB = [&](int k0, int buf) {
    gl_lds16(&Wt[brow * K + k0 + bcol], &Bs[buf][(w * 32) * 32]);
    gl_lds16(&Wt[(brow + 16) * K + k0 + bcol], &Bs[buf][(w * 32 + 16) * 32]);
  };
  auto stageA = [&](int buf) {
#pragma unroll
    for (int i = 0; i < 4; i++) {
      float x0 = pa[i].x, x1 = pa[i].y, x2 = pa[i].z, x3 = pa[i].w;
      if (DUAL) { x0 += pa2[i].x; x1 += pa2[i].y; x2 += pa2[i].z; x3 += pa2[i].w; }
      *(s4v*)&As[buf][(am + i * 32) * 40 + ak] =
          (s4v){f2bs(x0), f2bs(x1), f2bs(x2), f2bs(x3)};
    }
  };

  fx4 acc[4][4] = {};
  loadA(0);
  glB(0, 0);
  stageA(0);
  __syncthreads();
  int cur = 0;
  for (int k0 = 0; k0 < K; k0 += 32) {
    const int more = (k0 + 32 < K);
    if (more) {
      loadA(k0 + 32);        // f32 A regs in flight under MFMAs
      glB(k0 + 32, cur ^ 1); // weights stream direct to other LDS buffer
    }
    s8v af[4], bfr[4];
#pragma unroll
    for (int f = 0; f < 4; f++) {
      af[f] = *(s8v*)&As[cur][(wr * 64 + f * 16 + lm) * 40 + quad * 8];
      bfr[f] = *(s8v*)&Bs[cur][(wc * 64 + f * 16 + lm) * 32 + quad * 8];
    }
#pragma unroll
    for (int fm = 0; fm < 4; fm++)
#pragma unroll
      for (int fn = 0; fn < 4; fn++)
        acc[fm][fn] = __builtin_amdgcn_mfma_f32_16x16x32_bf16(
            af[fm], bfr[fn], acc[fm][fn], 0, 0, 0);
    if (more) stageA(cur ^ 1);
    __syncthreads();
    cur ^= 1;
  }
#pragma unroll
  for (int fn = 0; fn < 4; fn++) {
    const int n = n0 + wc * 64 + fn * 16 + lm;
    const float bb = bias[n];
#pragma unroll
    for (int fm = 0; fm < 4; fm++) {
      const int mbase = m0 + wr * 64 + fm * 16 + quad * 4;
#pragma unroll
      for (int r = 0; r < 4; r++)
        Cout[(size_t)(mbase + r) * N + n] = f2b(acc[fm][fn][r] + bb);
    }
  }
}

// ---------------------------------------------------------------------------
// Small-M GEMM, 64x64 tile: C[M,N] = (A (+A2))[M,K] @ Wt[N,K] + bias, f32 out.
// 256 thr = 4 waves of 32x32. Fixes occupancy: M=4096,N=256 gives 256 wg
// (vs 64 wg at 128-tile = 75% of CUs idle). Reg-staged A, reg-staged B.
// ---------------------------------------------------------------------------
template <int DUAL>
__global__ __launch_bounds__(256) void mgemm64_k(
    const float* __restrict__ A, const float* __restrict__ A2,
    const short* __restrict__ Wt, const float* __restrict__ bias,
    float* __restrict__ Cout, int M, int N, int K) {
  __shared__ short As[2][64 * 40];
  __shared__ short Bs[2][64 * 40];
  const int tid = threadIdx.x;
  const int lane = tid & 63, w = tid >> 6;
  const int wr = w >> 1, wc = w & 1;
  const int lm = lane & 15, quad = lane >> 4;
  const int nwg = gridDim.x * gridDim.y;
  const int ib = blockIdx.y * gridDim.x + blockIdx.x;
  const int id = (ib & 7) * (nwg >> 3) + (ib >> 3);
  const int m0 = (id / gridDim.x) * 64;
  const int n0 = (id % gridDim.x) * 64;

  const int am = tid >> 2, ak = (tid & 3) * 8;  // A: row am, 8 f32 (2 float4)
  const int bn = tid >> 2, bc = (tid & 3) * 8;  // B: row bn, one s8v

  float4 pa0, pa1, qa0, qa1;
  s8v pb;
  auto loadT = [&](int k0) {
    pa0 = *(const float4*)&A[(size_t)(m0 + am) * K + k0 + ak];
    pa1 = *(const float4*)&A[(size_t)(m0 + am) * K + k0 + ak + 4];
    if (DUAL) {
      qa0 = *(const float4*)&A2[(size_t)(m0 + am) * K + k0 + ak];
      qa1 = *(const float4*)&A2[(size_t)(m0 + am) * K + k0 + ak + 4];
    }
    pb = *(const s8v*)&Wt[(size_t)(n0 + bn) * K + k0 + bc];
  };
  auto stageT = [&](int buf) {
    float4 u = pa0, v = pa1;
    if (DUAL) {
      u.x += qa0.x; u.y += qa0.y; u.z += qa0.z; u.w += qa0.w;
      v.x += qa1.x; v.y += qa1.y; v.z += qa1.z; v.w += qa1.w;
    }
    *(s4v*)&As[buf][am * 40 + ak] = (s4v){f2bs(u.x), f2bs(u.y), f2bs(u.z), f2bs(u.w)};
    *(s4v*)&As[buf][am * 40 + ak + 4] = (s4v){f2bs(v.x), f2bs(v.y), f2bs(v.z), f2bs(v.w)};
    *(s8v*)&Bs[buf][bn * 40 + bc] = pb;
  };

  fx4 acc[2][2] = {};
  loadT(0);
  stageT(0);
  __syncthreads();
  int cur = 0;
  for (int k0 = 0; k0 < K; k0 += 32) {
    const int more = (k0 + 32 < K);
    if (more) loadT(k0 + 32);
    s8v af[2], bfr[2];
#pragma unroll
    for (int f = 0; f < 2; f++) {
      af[f] = *(s8v*)&As[cur][(wr * 32 + f * 16 + lm) * 40 + quad * 8];
      bfr[f] = *(s8v*)&Bs[cur][(wc * 32 + f * 16 + lm) * 40 + quad * 8];
    }
#pragma unroll
    for (int fm = 0; fm < 2; fm++)
#pragma unroll
      for (int fn = 0; fn < 2; fn++)
        acc[fm][fn] = __builtin_amdgcn_mfma_f32_16x16x32_bf16(
            af[fm], bfr[fn], acc[fm][fn], 0, 0, 0);
    if (more) stageT(cur ^ 1);
    __syncthreads();
    cur ^= 1;
  }
#pragma unroll
  for (int fn = 0; fn < 2; fn++) {
    const int n = n0 + wc * 32 + fn * 16 + lm;
    const float bb = bias[n];
#pragma unroll
    for (int fm = 0; fm < 2; fm++) {
      const int mbase = m0 + wr * 32 + fm * 16 + quad * 4;
#pragma unroll
      for (int r = 0; r < 4; r++)
        Cout[(size_t)(mbase + r) * N + n] = acc[fm][fn][r] + bb;
    }
  }
}

// ---------------------------------------------------------------------------
// MFMA GEMM 128x128 (R2 version), used for FFN1 (grid already 256 wg).
// ---------------------------------------------------------------------------
template <int DUAL, int RELU, int OUTBF>
__global__ __launch_bounds__(256) void mgemm_k(
    const float* __restrict__ A, const float* __restrict__ A2,
    const short* __restrict__ Wt, const float* __restrict__ bias,
    void* __restrict__ Cout, int M, int N, int K) {
  __shared__ short As[2][128 * 40];
  __shared__ short Bs[2][128 * 40];
  const int tid = threadIdx.x;
  const int lane = tid & 63, w = tid >> 6;
  const int wr = w >> 1, wc = w & 1;
  const int lm = lane & 15, quad = lane >> 4;
  const int nwg = gridDim.x * gridDim.y;
  const int ib = blockIdx.y * gridDim.x + blockIdx.x;
  const int id = (ib & 7) * (nwg >> 3) + (ib >> 3);
  const int m0 = (id / gridDim.x) * 128;
  const int n0 = (id % gridDim.x) * 128;

  const int am = tid >> 3, ak = (tid & 7) * 4;

  float4 pa[4], pa2[4];
  s8v pb[2];
  auto loadT = [&](int k0) {
#pragma unroll
    for (int i = 0; i < 4; i++) {
      pa[i] = *(const float4*)&A[(size_t)(m0 + am + i * 32) * K + k0 + ak];
      if (DUAL)
        pa2[i] = *(const float4*)&A2[(size_t)(m0 + am + i * 32) * K + k0 + ak];
    }
#pragma unroll
    for (int i = 0; i < 2; i++) {
      int unit = tid + i * 256;
      pb[i] = *(const s8v*)&Wt[(size_t)(n0 + (unit >> 2)) * K + k0 +
                               (unit & 3) * 8];
    }
  };
  auto stageT = [&](int buf) {
#pragma unroll
    for (int i = 0; i < 4; i++) {
      float x0 = pa[i].x, x1 = pa[i].y, x2 = pa[i].z, x3 = pa[i].w;
      if (DUAL) { x0 += pa2[i].x; x1 += pa2[i].y; x2 += pa2[i].z; x3 += pa2[i].w; }
      s4v sv = {f2bs(x0), f2bs(x1), f2bs(x2), f2bs(x3)};
      *(s4v*)&As[buf][(am + i * 32) * 40 + ak] = sv;
    }
#pragma unroll
    for (int i = 0; i < 2; i++) {
      int unit = tid + i * 256;
      *(s8v*)&Bs[buf][(unit >> 2) * 40 + (unit & 3) * 8] = pb[i];
    }
  };

  fx4 acc[4][4] = {};
  loadT(0);
  stageT(0);
  __syncthreads();
  int cur = 0;
  for (int k0 = 0; k0 < K; k0 += 32) {
    const int more = (k0 + 32 < K);
    if (more) loadT(k0 + 32);
    s8v af[4], bfr[4];
#pragma unroll
    for (int f = 0; f < 4; f++) {
      af[f] = *(s8v*)&As[cur][(wr * 64 + f * 16 + lm) * 40 + quad * 8];
      bfr[f] = *(s8v*)&Bs[cur][(wc * 64 + f * 16 + lm) * 40 + quad * 8];
    }
#pragma unroll
    for (int fm = 0; fm < 4; fm++)
#pragma unroll
      for (int fn = 0; fn < 4; fn++)
        acc[fm][fn] = __builtin_amdgcn_mfma_f32_16x16x32_bf16(
            af[fm], bfr[fn], acc[fm][fn], 0, 0, 0);
    if (more) stageT(cur ^ 1);
    __syncthreads();
    cur ^= 1;
  }
#pragma unroll
  for (int fn = 0; fn < 4; fn++) {
    const int n = n0 + wc * 64 + fn * 16 + lm;
    const float bb = bias[n];
#pragma unroll
    for (int fm = 0; fm < 4; fm++) {
      const int mbase = m0 + wr * 64 + fm * 16 + quad * 4;
#pragma unroll
      for (int r = 0; r < 4; r++) {
        float v = acc[fm][fn][r] + bb;
        if (RELU) v = fmaxf(v, 0.0f);
        const size_t off = (size_t)(mbase + r) * N + n;
        if (OUTBF)
          ((bf16*)Cout)[off] = f2b(v);
        else
          ((float*)Cout)[off] = v;
      }
    }
  }
}

// ---------------------------------------------------------------------------
// Flash-style MFMA self-attention, KV-split by 2 (flash-decoding).
// ---------------------------------------------------------------------------
__global__ __launch_bounds__(256) void sa_flash_k(
    const float* __restrict__ qh, const float* __restrict__ kh,
    const float* __restrict__ vh, float* __restrict__ op0,
    float* __restrict__ op1, float* __restrict__ mlb) {
  __shared__ short Ks[64 * 72];
  __shared__ short Vt[32 * 72];
  __shared__ short Ps[64 * 72];
  const int qt = blockIdx.x, h = blockIdx.y;
  const int b = blockIdx.z >> 1, half = blockIdx.z & 1;
  const int tid = threadIdx.x;
  const int w = tid >> 6, lane = tid & 63;
  const int lm = lane & 15, quad = lane >> 4;
  const size_t rowbase = (size_t)(b * NQT) * DM + h * DHSA;
  float* __restrict__ opart = half ? op1 : op0;
  float* __restrict__ ml = mlb + (size_t)half * (32768 * 2);

  s8v aq;
  {
    const int qrow = qt * 64 + w * 16 + lm;
    const float* qp = &qh[rowbase + (size_t)qrow * DM + quad * 8];
    const float4 q0 = *(const float4*)qp;
    const float4 q1 = *(const float4*)(qp + 4);
    const float sc = 0.17677669529663687f;
    aq = (s8v){f2bs(q0.x * sc), f2bs(q0.y * sc), f2bs(q0.z * sc), f2bs(q0.w * sc),
               f2bs(q1.x * sc), f2bs(q1.y * sc), f2bs(q1.z * sc), f2bs(q1.w * sc)};
  }

  fx4 o0 = {}, o1 = {};
  float mrun[4] = {-1e30f, -1e30f, -1e30f, -1e30f};
  float lrun[4] = {0.f, 0.f, 0.f, 0.f};
  const int jr = tid >> 2;
  const int d0 = (tid & 3) * 8;

  for (int jt = half * 8; jt < half * 8 + 8; jt++) {
    __syncthreads();
    {
      const size_t rb = rowbase + (size_t)(jt * 64 + jr) * DM + d0;
      const float4 k0 = *(const float4*)&kh[rb];
      const float4 k1 = *(const float4*)&kh[rb + 4];
      *(s8v*)&Ks[jr * 72 + d0] = pack8(k0, k1);
      const float4 v0 = *(const float4*)&vh[rb];
      const float4 v1 = *(const float4*)&vh[rb + 4];
      Vt[(d0 + 0) * 72 + jr] = f2bs(v0.x);
      Vt[(d0 + 1) * 72 + jr] = f2bs(v0.y);
      Vt[(d0 + 2) * 72 + jr] = f2bs(v0.z);
      Vt[(d0 + 3) * 72 + jr] = f2bs(v0.w);
      Vt[(d0 + 4) * 72 + jr] = f2bs(v1.x);
      Vt[(d0 + 5) * 72 + jr] = f2bs(v1.y);
      Vt[(d0 + 6) * 72 + jr] = f2bs(v1.z);
      Vt[(d0 + 7) * 72 + jr] = f2bs(v1.w);
    }
    __syncthreads();
    fx4 s[4];
    const fx4 zero = {};
#pragma unroll
    for (int nf = 0; nf < 4; nf++) {
      s8v kb = *(const s8v*)&Ks[(nf * 16 + lm) * 72 + quad * 8];
      s[nf] = __builtin_amdgcn_mfma_f32_16x16x32_bf16(aq, kb, zero, 0, 0, 0);
    }
#pragma unroll
    for (int r = 0; r < 4; r++) {
      float mx = fmaxf(fmaxf(s[0][r], s[1][r]), fmaxf(s[2][r], s[3][r]));
#pragma unroll
      for (int off = 8; off >= 1; off >>= 1)
        mx = fmaxf(mx, __shfl_xor(mx, off, 64));
      const float mnew = fmaxf(mrun[r], mx);
      const float corr = expf(mrun[r] - mnew);
      mrun[r] = mnew;
      float p0 = expf(s[0][r] - mnew);
      float p1 = expf(s[1][r] - mnew);
      float p2 = expf(s[2][r] - mnew);
      float p3 = expf(s[3][r] - mnew);
      float rs = p0 + p1 + p2 + p3;
#pragma unroll
      for (int off = 8; off >= 1; off >>= 1) rs += __shfl_xor(rs, off, 64);
      lrun[r] = lrun[r] * corr + rs;
      o0[r] *= corr;
      o1[r] *= corr;
      s[0][r] = p0; s[1][r] = p1; s[2][r] = p2; s[3][r] = p3;
    }
#pragma unroll
    for (int nf = 0; nf < 4; nf++)
#pragma unroll
      for (int r = 0; r < 4; r++)
        Ps[(w * 16 + quad * 4 + r) * 72 + nf * 16 + lm] = f2bs(s[nf][r]);
#pragma unroll
    for (int ks = 0; ks < 2; ks++) {
      s8v pf = *(const s8v*)&Ps[(w * 16 + lm) * 72 + ks * 32 + quad * 8];
      s8v vb0 = *(const s8v*)&Vt[lm * 72 + ks * 32 + quad * 8];
      s8v vb1 = *(const s8v*)&Vt[(16 + lm) * 72 + ks * 32 + quad * 8];
      o0 = __builtin_amdgcn_mfma_f32_16x16x32_bf16(pf, vb0, o0, 0, 0, 0);
      o1 = __builtin_amdgcn_mfma_f32_16x16x32_bf16(pf, vb1, o1, 0, 0, 0);
    }
  }
#pragma unroll
  for (int r = 0; r < 4; r++) {
    const int row = qt * 64 + w * 16 + quad * 4 + r;
    const size_t base = rowbase + (size_t)row * DM;
    opart[base + lm] = o0[r];
    opart[base + 16 + lm] = o1[r];
    if (lm == 0) {
      const int rowid = (b * 8 + h) * 1024 + row;
      ml[(size_t)rowid * 2] = mrun[r];
      ml[(size_t)rowid * 2 + 1] = lrun[r];
    }
  }
}

// Merge the two KV-halves: out = (o0*w0 + o1*w1) / (l0*w0 + l1*w1).
__global__ __launch_bounds__(256) void sa_merge_k(
    const float* __restrict__ op0, const float* __restrict__ op1,
    const float* __restrict__ mlb, float* __restrict__ outp) {
  const int t = blockIdx.x * 256 + threadIdx.x;  // 0..1048575
  const int d = t & 31;
  const int rowid = t >> 5;  // (b*8+h)*1024 + n
  const int n = rowid & 1023, h = (rowid >> 10) & 7, b = rowid >> 13;
  const size_t addr = ((size_t)(b * NQT + n)) * DM + h * DHSA + d;
  const float m0 = mlb[(size_t)rowid * 2], l0 = mlb[(size_t)rowid * 2 + 1];
  const float m1 = mlb[65536 + (size_t)rowid * 2];
  const float l1 = mlb[65536 + (size_t)rowid * 2 + 1];
  const float M = fmaxf(m0, m1);
  const float w0 = expf(m0 - M), w1 = expf(m1 - M);
  const float inv = 1.0f / (l0 * w0 + l1 * w1);
  outp[addr] = (op0[addr] * w0 + op1[addr] * w1) * inv;
}

// ---------------------------------------------------------------------------
// ref = sigmoid(x1 @ Wref + bref), off = x1 @ Woff + boff  (per query row)
// ---------------------------------------------------------------------------
__global__ __launch_bounds__(128) void refoff_k(
    const float* __restrict__ x1, const float* __restrict__ Wref,
    const float* __restrict__ bref, const float* __restrict__ Woff,
    const float* __restrict__ boff, float* __restrict__ refb,
    float* __restrict__ offb) {
  __shared__ float xs[256];
  const int row = blockIdx.x;
  const int tid = threadIdx.x;
  xs[tid] = x1[(size_t)row * DM + tid];
  xs[tid + 128] = x1[(size_t)row * DM + tid + 128];
  __syncthreads();
  if (tid < 3) {
    float s = bref[tid];
    for (int d = 0; d < 256; d++) s = fmaf(xs[d], Wref[d * 3 + tid], s);
    refb[(size_t)row * 3 + tid] = 1.0f / (1.0f + expf(-s));
  } else if (tid < 99) {
    int o = tid - 3;
    float s = boff[o];
    for (int d = 0; d < 256; d++) s = fmaf(xs[d], Woff[d * 96 + o], s);
    offb[(size_t)row * 96 + o] = s;
  }
}

// ---------------------------------------------------------------------------
// Shared trilinear corner computation for one (bn, h).
// ---------------------------------------------------------------------------
__device__ __forceinline__ void calc_corners(
    const float* __restrict__ refb, const float* __restrict__ offb, int bn,
    int h, int (&idxs)[NPT][8], float (&wts)[NPT][8]) {
  const float rt = refb[bn * 3 + 0], ry = refb[bn * 3 + 1], rx = refb[bn * 3 + 2];
  const float* ofp = &offb[(size_t)bn * 96 + h * 12];
#pragma unroll
  for (int p = 0; p < NPT; p++) {
    float lt = rt + ofp[p * 3 + 0] * 0.5f;      // OFFSET_SCALE / T
    float ly = ry + ofp[p * 3 + 1] * 0.03125f;  // OFFSET_SCALE / H
    float lx = rx + ofp[p * 3 + 2] * 0.03125f;  // OFFSET_SCALE / W
    float pt = fminf(fmaxf(lt, 0.f), 1.f) * (TT - 1);
    float py = fminf(fmaxf(ly, 0.f), 1.f) * (HH - 1);
    float px = fminf(fmaxf(lx, 0.f), 1.f) * (WW - 1);
    float f0t = floorf(pt), f0y = floorf(py), f0x = floorf(px);
    float frt = pt - f0t, fry = py - f0y, frx = px - f0x;
    int t0 = (int)f0t, y0 = (int)f0y, x0 = (int)f0x;
    int t1 = min(t0 + 1, TT - 1), y1 = min(y0 + 1, HH - 1), x1 = min(x0 + 1, WW - 1);
    float wt0 = 1.f - frt, wy0 = 1.f - fry, wx0 = 1.f - frx;
#pragma unroll
    for (int c = 0; c < 8; c++) {
      int dt = c >> 2, dy = (c >> 1) & 1, dx = c & 1;
      int ct = dt ? t1 : t0, cy = dy ? y1 : y0, cx = dx ? x1 : x0;
      idxs[p][c] = ct * (HH * WW) + cy * WW + cx;
      wts[p][c] = (dt ? frt : wt0) * (dy ? fry : wy0) * (dx ? frx : wx0);
    }
  }
}

// ---------------------------------------------------------------------------
// Sample k-volume at the 4 points, dot with q -> 4 logits into slots.
// ---------------------------------------------------------------------------
__global__ __launch_bounds__(256) void ca_logits_k(
    const float* __restrict__ qh, const float* __restrict__ refb,
    const float* __restrict__ offb, const bf16* __restrict__ vol,
    float* __restrict__ logits, int slot) {
  const int wid = (blockIdx.x * blockDim.x + threadIdx.x) >> 6;  // 0..32767
  const int lane = threadIdx.x & 63;
  const int h = wid & 7;
  const int bn = wid >> 3;  // 0..4095
  const int b = bn >> 10;
  const float q = qh[(size_t)bn * CAI + h * CADH + lane];
  int idxs[NPT][8];
  float wts[NPT][8];
  calc_corners(refb, offb, bn, h, idxs, wts);
  const size_t volbase = (size_t)b * LVOL * CAI + h * CADH + lane;
  float* lp = logits + ((size_t)bn * CAH + h) * 8 + slot;
#pragma unroll
  for (int p = 0; p < NPT; p++) {
    float ks = 0.f;
#pragma unroll
    for (int c = 0; c < 8; c++)
      ks = fmaf(wts[p][c], b2f(vol[volbase + (size_t)idxs[p][c] * CAI]), ks);
    float li = wave_sum64(q * ks) * 0.125f;  // 1/sqrt(64)
    if (lane == p) lp[p] = li;
  }
}

// ---------------------------------------------------------------------------
// Joint softmax over the 8 logits (4 img + 4 flow) per (bn, h), in place.
// ---------------------------------------------------------------------------
__global__ __launch_bounds__(256) void ca_softmax_k(float* __restrict__ logits) {
  const int i = blockIdx.x * blockDim.x + threadIdx.x;  // 0..32767
  float* p = logits + (size_t)i * 8;
  float v[8], m = -1e30f;
#pragma unroll
  for (int j = 0; j < 8; j++) { v[j] = p[j]; m = fmaxf(m, v[j]); }
  float s = 0.f;
#pragma unroll
  for (int j = 0; j < 8; j++) { v[j] = expf(v[j] - m); s += v[j]; }
  const float inv = 1.0f / s;
#pragma unroll
  for (int j = 0; j < 8; j++) p[j] = v[j] * inv;
}

// ---------------------------------------------------------------------------
// Sample v-volume, weight by attn slots, accumulate into f32 acc.
// ---------------------------------------------------------------------------
template <int FIRST>
__global__ __launch_bounds__(256) void ca_acc_k(
    const float* __restrict__ refb, const float* __restrict__ offb,
    const bf16* __restrict__ vol, const float* __restrict__ attn,
    float* __restrict__ acc, int slot) {
  const int wid = (blockIdx.x * blockDim.x + threadIdx.x) >> 6;
  const int lane = threadIdx.x & 63;
  const int h = wid & 7;
  const int bn = wid >> 3;
  const int b = bn >> 10;
  int idxs[NPT][8];
  float wts[NPT][8];
  calc_corners(refb, offb, bn, h, idxs, wts);
  const size_t volbase = (size_t)b * LVOL * CAI + h * CADH + lane;
  const float* ap = attn + ((size_t)bn * CAH + h) * 8 + slot;
  const size_t off = (size_t)bn * CAI + h * CADH + lane;
  float a = FIRST ? 0.f : acc[off];
#pragma unroll
  for (int p = 0; p < NPT; p++) {
    float vs = 0.f;
#pragma unroll
    for (int c = 0; c < 8; c++)
      vs = fmaf(wts[p][c], b2f(vol[volbase + (size_t)idxs[p][c] * CAI]), vs);
    a = fmaf(ap[p], vs, a);
  }
  acc[off] = a;
}

// ---------------------------------------------------------------------------
// LayerNorm over 256 dims of (res + x); one wave per row; f32 in/out.
// ---------------------------------------------------------------------------
__global__ __launch_bounds__(256) void ln_k(
    const float* __restrict__ resv, const float* __restrict__ x,
    const float* __restrict__ g, const float* __restrict__ bb,
    float* __restrict__ of) {
  const int row = (blockIdx.x * blockDim.x + threadIdx.x) >> 6;
  const int lane = threadIdx.x & 63;
  const size_t base = (size_t)row * DM;
  float v[4];
#pragma unroll
  for (int i = 0; i < 4; i++) {
    int d = lane + i * 64;
    v[i] = resv[base + d] + x[base + d];
  }
  float s = wave_sum64(v[0] + v[1] + v[2] + v[3]);
  const float mean = s * (1.0f / 256.0f);
  float vs = 0.f;
#pragma unroll
  for (int i = 0; i < 4; i++) { float d0 = v[i] - mean; vs = fmaf(d0, d0, vs); }
  vs = wave_sum64(vs);
  const float rstd = rsqrtf(vs * (1.0f / 256.0f) + 1e-5f);
#pragma unroll
  for (int i = 0; i < 4; i++) {
    int d = lane + i * 64;
    of[base + d] = (v[i] - mean) * rstd * g[d] + bb[d];
  }
}

extern "C" void kernel_launch(void* const* d_in, const int* in_sizes, int n_in,
                              void* d_out, int out_size, void* d_ws,
                              size_t ws_size, hipStream_t stream) {
  const float* query = (const float*)d_in[0];
  const float* qpos = (const float*)d_in[1];
  const float* img = (const float*)d_in[2];
  const float* flow = (const float*)d_in[3];
  const float* pos = (const float*)d_in[4];
  const float* sa_Wq = (const float*)d_in[6];
  const float* sa_Wk = (const float*)d_in[7];
  const float* sa_Wv = (const float*)d_in[8];
  const float* sa_Wo = (const float*)d_in[9];
  const float* sa_bq = (const float*)d_in[10];
  const float* sa_bk = (const float*)d_in[11];
  const float* sa_bv = (const float*)d_in[12];
  const float* sa_bo = (const float*)d_in[13];
  const float* ln1_b = (const float*)d_in[14];
  const float* ln2_b = (const float*)d_in[15];
  const float* ln3_b = (const float*)d_in[16];
  const float* ln1_g = (const float*)d_in[17];
  const float* ln2_g = (const float*)d_in[18];
  const float* ln3_g = (const float*)d_in[19];
  const float* ca_Wq = (const float*)d_in[20];
  const float* ca_bq = (const float*)d_in[21];
  const float* ca_Wk = (const float*)d_in[22];
  const float* ca_bk = (const float*)d_in[23];
  const float* ca_Wv = (const float*)d_in[24];
  const float* ca_bv = (const float*)d_in[25];
  const float* ca_Wref = (const float*)d_in[26];
  const float* ca_bref = (const float*)d_in[27];
  const float* ca_Woff = (const float*)d_in[28];
  const float* ca_boff = (const float*)d_in[29];
  const float* ca_Wo = (const float*)d_in[30];
  const float* ca_bo = (const float*)d_in[31];
  const float* ffn_W1 = (const float*)d_in[32];
  const float* ffn_b1 = (const float*)d_in[33];
  const float* ffn_W2 = (const float*)d_in[34];
  const float* ffn_b2 = (const float*)d_in[35];

  const int MQ = BQ * NQT;   // 4096
  const int MV = BQ * LVOL;  // 65536
  const size_t MB = 1024 * 1024;

  char* r0 = (char*)d_ws;  // 64 MB time-shared region
  char* w = r0 + 64 * MB;
  auto alloc = [&](size_t n) {
    char* p = w;
    w += (n + 255) & ~(size_t)255;
    return p;
  };
  float* x1_f = (float*)alloc((size_t)MQ * DM * 4);
  float* ca_qh = (float*)alloc((size_t)MQ * CAI * 4);
  float* refb = (float*)alloc((size_t)MQ * 3 * 4);
  float* offb = (float*)alloc((size_t)MQ * 96 * 4);
  float* logits = (float*)alloc((size_t)MQ * CAH * 8 * 4);
  float* ca_acc = (float*)alloc((size_t)MQ * CAI * 4);
  // transposed bf16 weights [N][K]
  short* WtsaQ = (short*)alloc((size_t)DM * DM * 2);
  short* WtsaK = (short*)alloc((size_t)DM * DM * 2);
  short* WtsaV = (short*)alloc((size_t)DM * DM * 2);
  short* WtsaO = (short*)alloc((size_t)DM * DM * 2);
  short* Wtcaq = (short*)alloc((size_t)CAI * DM * 2);
  short* Wtk = (short*)alloc((size_t)CAI * DM * 2);
  short* Wtv = (short*)alloc((size_t)CAI * DM * 2);
  short* Wtcao = (short*)alloc((size_t)DM * CAI * 2);
  short* Wtf1 = (short*)alloc((size_t)DFFN * DM * 2);
  short* Wtf2 = (short*)alloc((size_t)DM * DFFN * 2);
  if ((size_t)(w - (char*)d_ws) > ws_size) return;  // graceful fail (diagnostic)

  // SA-phase overlays in region0
  float* qh_sa = (float*)(r0 + 0 * MB);
  float* kh_sa = (float*)(r0 + 4 * MB);
  float* vh_sa = (float*)(r0 + 8 * MB);
  float* sa_att = (float*)(r0 + 12 * MB);
  float* sa_proj = (float*)(r0 + 16 * MB);
  float* o_p0 = (float*)(r0 + 20 * MB);   // 4 MB unnormalized partial O (half 0)
  float* o_p1 = (float*)(r0 + 24 * MB);   // 4 MB (half 1)
  float* mlb = (float*)(r0 + 28 * MB);    // 2 x 32768 x 2 f32 = 512 KB
  // CA volume overlay
  bf16* vol = (bf16*)r0;  // 64 MB
  // post-CA overlays
  float* ca_o = (float*)(r0 + 0 * MB);
  float* x2_f = (float*)(r0 + 4 * MB);
  float* ffn_h = (float*)(r0 + 8 * MB);   // 16 MB
  float* ffn_o = (float*)(r0 + 24 * MB);

  dim3 blk(256);
  // --- all weight transposes in one launch ---
  WtransArgs wa;
  wa.W[0] = sa_Wq;  wa.Wt[0] = WtsaQ;
  wa.W[1] = sa_Wk;  wa.Wt[1] = WtsaK;
  wa.W[2] = sa_Wv;  wa.Wt[2] = WtsaV;
  wa.W[3] = sa_Wo;  wa.Wt[3] = WtsaO;
  wa.W[4] = ca_Wq;  wa.Wt[4] = Wtcaq;
  wa.W[5] = ca_Wk;  wa.Wt[5] = Wtk;
  wa.W[6] = ca_Wv;  wa.Wt[6] = Wtv;
  wa.W[7] = ffn_W1; wa.Wt[7] = Wtf1;
  wa.W[8] = ca_Wo;  wa.Wt[8] = Wtcao;
  wa.W[9] = ffn_W2; wa.Wt[9] = Wtf2;
  wtrans_all_k<<<dim3(5120), blk, 0, stream>>>(wa);
  // --- self-attention (64x64-tile GEMMs: 256 wg each) ---
  mgemm64_k<1><<<dim3(DM / 64, MQ / 64), blk, 0, stream>>>(query, qpos, WtsaQ, sa_bq, qh_sa, MQ, DM, DM);
  mgemm64_k<1><<<dim3(DM / 64, MQ / 64), blk, 0, stream>>>(query, qpos, WtsaK, sa_bk, kh_sa, MQ, DM, DM);
  mgemm64_k<0><<<dim3(DM / 64, MQ / 64), blk, 0, stream>>>(query, query, WtsaV, sa_bv, vh_sa, MQ, DM, DM);
  sa_flash_k<<<dim3(16, 8, 8), blk, 0, stream>>>(qh_sa, kh_sa, vh_sa, o_p0, o_p1, mlb);
  sa_merge_k<<<dim3(4096), blk, 0, stream>>>(o_p0, o_p1, mlb, sa_att);
  mgemm64_k<0><<<dim3(DM / 64, MQ / 64), blk, 0, stream>>>(sa_att, sa_att, WtsaO, sa_bo, sa_proj, MQ, DM, DM);
  ln_k<<<dim3(MQ / 4), blk, 0, stream>>>(query, sa_proj, ln1_g, ln1_b, x1_f);
  // --- deformable cross-attention (fused f32->bf16 volume GEMMs) ---
  mgemm64_k<0><<<dim3(CAI / 64, MQ / 64), blk, 0, stream>>>(x1_f, x1_f, Wtcaq, ca_bq, ca_qh, MQ, CAI, DM);
  refoff_k<<<dim3(MQ), dim3(128), 0, stream>>>(x1_f, ca_Wref, ca_bref, ca_Woff, ca_boff, refb, offb);
  vgemm_k<1><<<dim3(CAI / 128, MV / 128), blk, 0, stream>>>(pos, img, Wtk, ca_bk, vol, MV, CAI, DM);
  ca_logits_k<<<dim3(8192), blk, 0, stream>>>(ca_qh, refb, offb, vol, logits, 0);
  vgemm_k<1><<<dim3(CAI / 128, MV / 128), blk, 0, stream>>>(pos, flow, Wtk, ca_bk, vol, MV, CAI, DM);
  ca_logits_k<<<dim3(8192), blk, 0, stream>>>(ca_qh, refb, offb, vol, logits, 4);
  ca_softmax_k<<<dim3(128), blk, 0, stream>>>(logits);
  vgemm_k<0><<<dim3(CAI / 128, MV / 128), blk, 0, stream>>>(img, img, Wtv, ca_bv, vol, MV, CAI, DM);
  ca_acc_k<1><<<dim3(8192), blk, 0, stream>>>(refb, offb, vol, logits, ca_acc, 0);
  vgemm_k<0><<<dim3(CAI / 128, MV / 128), blk, 0, stream>>>(flow, flow, Wtv, ca_bv, vol, MV, CAI, DM);
  ca_acc_k<0><<<dim3(8192), blk, 0, stream>>>(refb, offb, vol, logits, ca_acc, 4);
  mgemm64_k<0><<<dim3(DM / 64, MQ / 64), blk, 0, stream>>>(ca_acc, ca_acc, Wtcao, ca_bo, ca_o, MQ, DM, CAI);
  ln_k<<<dim3(MQ / 4), blk, 0, stream>>>(x1_f, ca_o, ln2_g, ln2_b, x2_f);
  // --- FFN ---
  mgemm_k<0, 1, 0><<<dim3(DFFN / 128, MQ / 128), blk, 0, stream>>>(x2_f, x2_f, Wtf1, ffn_b1, (void*)ffn_h, MQ, DFFN, DM);
  mgemm64_k<0><<<dim3(DM / 64, MQ / 64), blk, 0, stream>>>(ffn_h, ffn_h, Wtf2, ffn_b2, ffn_o, MQ, DM, DFFN);
  ln_k<<<dim3(MQ / 4), blk, 0, stream>>>(x2_f, ffn_o, ln3_g, ln3_b, (float*)d_out);
}